// Round 1
// baseline (643.584 us; speedup 1.0000x reference)
//
#include <hip/hip_runtime.h>

typedef __bf16 bf16;
typedef __bf16 bf16x4 __attribute__((ext_vector_type(4)));
typedef __bf16 bf16x8 __attribute__((ext_vector_type(8)));
typedef float  f32x4  __attribute__((ext_vector_type(4)));

#define BB 4
#define SEQ 2048
#define CH 768
#define NH 12
#define HD 64
#define DFF 3072
#define MROWS (BB * SEQ)   // 8192
#define C3 (3 * CH)        // 2304

__device__ inline f32x4 mfma16(bf16x8 a, bf16x8 b, f32x4 c) {
    return __builtin_amdgcn_mfma_f32_16x16x32_bf16(a, b, c, 0, 0, 0);
}

// ---------------- fp32 -> bf16 convert (vectorized x4) ----------------
__global__ void cvt_f32_bf16(const float* __restrict__ in, bf16* __restrict__ out, int n) {
    int i = (blockIdx.x * blockDim.x + threadIdx.x) * 4;
    if (i + 3 >= n) {
        for (int j = 0; j < 4 && i + j < n; ++j) out[i + j] = (bf16)in[i + j];
        return;
    }
    f32x4 v = *(const f32x4*)&in[i];
    bf16x4 o;
    #pragma unroll
    for (int j = 0; j < 4; ++j) o[j] = (bf16)v[j];
    *(bf16x4*)&out[i] = o;
}

// ------------- transpose + convert: in fp32 [R, Cc] -> out bf16 [Cc, R] -------------
__global__ void transpose_cvt(const float* __restrict__ in, bf16* __restrict__ out, int R, int Cc) {
    __shared__ bf16 t[32][33];
    int tx = threadIdx.x & 31, ty = threadIdx.x >> 5;  // 256 threads: ty 0..7
    int c0 = blockIdx.x * 32, r0 = blockIdx.y * 32;
    #pragma unroll
    for (int i = 0; i < 32; i += 8)
        t[ty + i][tx] = (bf16)in[(size_t)(r0 + ty + i) * Cc + c0 + tx];
    __syncthreads();
    #pragma unroll
    for (int i = 0; i < 32; i += 8)
        out[(size_t)(c0 + ty + i) * R + r0 + tx] = t[tx][ty + i];
}

// ------------- V transpose: qkvb [B,S,3C] (V slice) -> vt [B*H, 64, S] -------------
__global__ void transpose_v(const bf16* __restrict__ qkvb, bf16* __restrict__ vt) {
    __shared__ bf16 t[32][33];
    int tx = threadIdx.x & 31, ty = threadIdx.x >> 5;
    int n0 = blockIdx.x * 32, d0 = blockIdx.y * 32, bh = blockIdx.z;
    int b = bh / NH, h = bh - b * NH;
    #pragma unroll
    for (int i = 0; i < 32; i += 8)
        t[ty + i][tx] = qkvb[((size_t)b * SEQ + n0 + ty + i) * C3 + 2 * CH + h * HD + d0 + tx];
    __syncthreads();
    #pragma unroll
    for (int i = 0; i < 32; i += 8)
        vt[((size_t)bh * HD + d0 + ty + i) * SEQ + n0 + tx] = t[tx][ty + i];
}

// ------------- GEMM: C[M,N] = A[M,K](bf16) * Bt[N,K]^T (bf16) + bias -------------
// OMODE: 0 = fp32 out, 1 = bf16 out, 2 = bf16 out with exact GELU
template <int OMODE>
__global__ __launch_bounds__(256) void gemm_bt(const bf16* __restrict__ A,
                                               const bf16* __restrict__ Bt,
                                               const float* __restrict__ bias,
                                               void* __restrict__ Cout,
                                               int M, int N, int K) {
    __shared__ __align__(16) bf16 As[128][40];
    __shared__ __align__(16) bf16 Bs[128][40];
    const int bm = blockIdx.y * 128, bn = blockIdx.x * 128;
    const int tid = threadIdx.x;
    const int lane = tid & 63, w = tid >> 6;
    const int wr = w >> 1, wc = w & 1;
    const int lr = lane & 15, lg = lane >> 4;

    f32x4 acc[4][4];
    #pragma unroll
    for (int i = 0; i < 4; ++i)
        #pragma unroll
        for (int j = 0; j < 4; ++j) acc[i][j] = (f32x4){0.f, 0.f, 0.f, 0.f};

    for (int k0 = 0; k0 < K; k0 += 32) {
        __syncthreads();
        #pragma unroll
        for (int i = 0; i < 2; ++i) {
            int q = tid + i * 256;
            int row = q >> 2, cc = q & 3;
            *(bf16x8*)&As[row][cc * 8] = *(const bf16x8*)&A[(size_t)(bm + row) * K + k0 + cc * 8];
            *(bf16x8*)&Bs[row][cc * 8] = *(const bf16x8*)&Bt[(size_t)(bn + row) * K + k0 + cc * 8];
        }
        __syncthreads();
        bf16x8 af[4], bfr[4];
        #pragma unroll
        for (int mi = 0; mi < 4; ++mi)
            af[mi] = *(const bf16x8*)&As[wr * 64 + mi * 16 + lr][lg * 8];
        #pragma unroll
        for (int ni = 0; ni < 4; ++ni)
            bfr[ni] = *(const bf16x8*)&Bs[wc * 64 + ni * 16 + lr][lg * 8];
        #pragma unroll
        for (int mi = 0; mi < 4; ++mi)
            #pragma unroll
            for (int ni = 0; ni < 4; ++ni)
                acc[mi][ni] = mfma16(af[mi], bfr[ni], acc[mi][ni]);
    }

    #pragma unroll
    for (int mi = 0; mi < 4; ++mi) {
        #pragma unroll
        for (int ni = 0; ni < 4; ++ni) {
            int col = bn + wc * 64 + ni * 16 + lr;
            float bsv = bias[col];
            #pragma unroll
            for (int r = 0; r < 4; ++r) {
                int row = bm + wr * 64 + mi * 16 + lg * 4 + r;
                float v = acc[mi][ni][r] + bsv;
                if (OMODE == 2) v = 0.5f * v * (1.0f + erff(v * 0.70710678118654752f));
                if (OMODE == 0)
                    ((float*)Cout)[(size_t)row * N + col] = v;
                else
                    ((bf16*)Cout)[(size_t)row * N + col] = (bf16)v;
            }
        }
    }
}

// ------------- flash attention: qkvb [B,S,3C], vt [B*H,64,S] -> outb [B,S,C] -------------
__global__ __launch_bounds__(256) void attn_kernel(const bf16* __restrict__ qkvb,
                                                   const bf16* __restrict__ vt,
                                                   bf16* __restrict__ outb) {
    __shared__ __align__(16) bf16 P[4][16][40];
    const int tid = threadIdx.x, w = tid >> 6, lane = tid & 63;
    const int lr = lane & 15, lg = lane >> 4;
    const int qt = blockIdx.x, bh = blockIdx.y;
    const int b = bh / NH, h = bh - b * NH;
    const int q0 = qt * 64 + w * 16;

    const bf16* qbase = qkvb + (size_t)b * SEQ * C3 + h * HD;
    const bf16* kbase = qbase + CH;
    const bf16* vbase = vt + (size_t)bh * HD * SEQ;

    bf16x8 qf[2];
    qf[0] = *(const bf16x8*)&qbase[(size_t)(q0 + lr) * C3 + lg * 8];
    qf[1] = *(const bf16x8*)&qbase[(size_t)(q0 + lr) * C3 + 32 + lg * 8];

    f32x4 o[4];
    #pragma unroll
    for (int dt = 0; dt < 4; ++dt) o[dt] = (f32x4){0.f, 0.f, 0.f, 0.f};
    float m[4], l[4];
    #pragma unroll
    for (int r = 0; r < 4; ++r) { m[r] = -3.0e38f; l[r] = 0.f; }

    for (int kv = 0; kv < SEQ; kv += 32) {
        f32x4 s0 = {0.f, 0.f, 0.f, 0.f}, s1 = {0.f, 0.f, 0.f, 0.f};
        bf16x8 k00 = *(const bf16x8*)&kbase[(size_t)(kv + lr) * C3 + lg * 8];
        bf16x8 k01 = *(const bf16x8*)&kbase[(size_t)(kv + lr) * C3 + 32 + lg * 8];
        bf16x8 k10 = *(const bf16x8*)&kbase[(size_t)(kv + 16 + lr) * C3 + lg * 8];
        bf16x8 k11 = *(const bf16x8*)&kbase[(size_t)(kv + 16 + lr) * C3 + 32 + lg * 8];
        s0 = mfma16(qf[0], k00, s0);
        s0 = mfma16(qf[1], k01, s0);
        s1 = mfma16(qf[0], k10, s1);
        s1 = mfma16(qf[1], k11, s1);

        float mx[4], p0[4], p1[4], a[4], rs[4];
        #pragma unroll
        for (int r = 0; r < 4; ++r) {
            s0[r] *= 0.125f;
            s1[r] *= 0.125f;
            mx[r] = fmaxf(s0[r], s1[r]);
        }
        #pragma unroll
        for (int off = 1; off < 16; off <<= 1)
            #pragma unroll
            for (int r = 0; r < 4; ++r) mx[r] = fmaxf(mx[r], __shfl_xor(mx[r], off));
        #pragma unroll
        for (int r = 0; r < 4; ++r) {
            float mn = fmaxf(m[r], mx[r]);
            a[r] = __expf(m[r] - mn);
            p0[r] = __expf(s0[r] - mn);
            p1[r] = __expf(s1[r] - mn);
            m[r] = mn;
            rs[r] = p0[r] + p1[r];
        }
        #pragma unroll
        for (int off = 1; off < 16; off <<= 1)
            #pragma unroll
            for (int r = 0; r < 4; ++r) rs[r] += __shfl_xor(rs[r], off);
        #pragma unroll
        for (int r = 0; r < 4; ++r) l[r] = l[r] * a[r] + rs[r];
        #pragma unroll
        for (int dt = 0; dt < 4; ++dt)
            #pragma unroll
            for (int r = 0; r < 4; ++r) o[dt][r] *= a[r];

        #pragma unroll
        for (int r = 0; r < 4; ++r) {
            P[w][lg * 4 + r][lr] = (bf16)p0[r];
            P[w][lg * 4 + r][16 + lr] = (bf16)p1[r];
        }
        asm volatile("s_waitcnt lgkmcnt(0)" ::: "memory");
        bf16x8 pa = *(const bf16x8*)&P[w][lr][lg * 8];
        #pragma unroll
        for (int dt = 0; dt < 4; ++dt) {
            bf16x8 vb = *(const bf16x8*)&vbase[(size_t)(dt * 16 + lr) * SEQ + kv + lg * 8];
            o[dt] = mfma16(pa, vb, o[dt]);
        }
        asm volatile("s_waitcnt lgkmcnt(0)" ::: "memory");
    }

    #pragma unroll
    for (int dt = 0; dt < 4; ++dt)
        #pragma unroll
        for (int r = 0; r < 4; ++r) {
            float val = o[dt][r] / l[r];
            outb[((size_t)b * SEQ + q0 + lg * 4 + r) * CH + h * HD + dt * 16 + lr] = (bf16)val;
        }
}

// ------------- fused residual add + LayerNorm -------------
__global__ __launch_bounds__(256) void add_ln(const float* __restrict__ x,
                                              const float* __restrict__ t,
                                              const float* __restrict__ g,
                                              const float* __restrict__ bt,
                                              float* __restrict__ y,
                                              bf16* __restrict__ yb) {
    const int row = blockIdx.x;
    const size_t base = (size_t)row * CH;
    const int tid = threadIdx.x;
    float v[3];
    #pragma unroll
    for (int k = 0; k < 3; ++k) {
        int c = tid + k * 256;
        v[k] = x[base + c] + t[base + c];
    }
    __shared__ float red[4];
    float s = v[0] + v[1] + v[2];
    #pragma unroll
    for (int off = 32; off >= 1; off >>= 1) s += __shfl_down(s, off);
    if ((tid & 63) == 0) red[tid >> 6] = s;
    __syncthreads();
    float mean = (red[0] + red[1] + red[2] + red[3]) * (1.0f / 768.0f);
    float q = 0.f;
    #pragma unroll
    for (int k = 0; k < 3; ++k) {
        float d = v[k] - mean;
        q += d * d;
    }
    __syncthreads();
    #pragma unroll
    for (int off = 32; off >= 1; off >>= 1) q += __shfl_down(q, off);
    if ((tid & 63) == 0) red[tid >> 6] = q;
    __syncthreads();
    float var = (red[0] + red[1] + red[2] + red[3]) * (1.0f / 768.0f);
    float rstd = rsqrtf(var + 1e-5f);
    #pragma unroll
    for (int k = 0; k < 3; ++k) {
        int c = tid + k * 256;
        float out = (v[k] - mean) * rstd * g[c] + bt[c];
        y[base + c] = out;
        if (yb) yb[base + c] = (bf16)out;
    }
}

extern "C" void kernel_launch(void* const* d_in, const int* in_sizes, int n_in,
                              void* d_out, int out_size, void* d_ws, size_t ws_size,
                              hipStream_t stream) {
    const float* x    = (const float*)d_in[0];
    const float* Wqkv = (const float*)d_in[1];
    const float* bqkv = (const float*)d_in[2];
    const float* Wproj= (const float*)d_in[3];
    const float* bproj= (const float*)d_in[4];
    const float* g1   = (const float*)d_in[5];
    const float* b1   = (const float*)d_in[6];
    const float* g2   = (const float*)d_in[7];
    const float* b2   = (const float*)d_in[8];
    const float* Wfc1 = (const float*)d_in[9];
    const float* bfc1 = (const float*)d_in[10];
    const float* Wfc2 = (const float*)d_in[11];
    const float* bfc2 = (const float*)d_in[12];

    char* ws = (char*)d_ws;
    size_t off = 0;
    auto alloc = [&](size_t bytes) -> void* {
        void* p = ws + off;
        off += (bytes + 255) & ~(size_t)255;
        return p;
    };

    bf16* xb     = (bf16*)alloc((size_t)MROWS * CH * 2);
    bf16* WqkvT  = (bf16*)alloc((size_t)C3 * CH * 2);
    bf16* WprojT = (bf16*)alloc((size_t)CH * CH * 2);
    bf16* Wfc1T  = (bf16*)alloc((size_t)DFF * CH * 2);
    bf16* Wfc2T  = (bf16*)alloc((size_t)CH * DFF * 2);
    bf16* qkvb   = (bf16*)alloc((size_t)MROWS * C3 * 2);
    bf16* vtb    = (bf16*)alloc((size_t)BB * NH * HD * SEQ * 2);
    bf16* attnb  = (bf16*)alloc((size_t)MROWS * CH * 2);
    float* tmp   = (float*)alloc((size_t)MROWS * CH * 4);
    float* y1    = (float*)alloc((size_t)MROWS * CH * 4);
    bf16* y1b    = (bf16*)alloc((size_t)MROWS * CH * 2);
    bf16* hb     = (bf16*)alloc((size_t)MROWS * DFF * 2);

    // 1. x -> bf16
    cvt_f32_bf16<<<(MROWS * CH / 4 + 255) / 256, 256, 0, stream>>>(x, xb, MROWS * CH);
    // 2. weight transposes (fp32 [K,N] -> bf16 [N,K])
    transpose_cvt<<<dim3(C3 / 32, CH / 32), 256, 0, stream>>>(Wqkv, WqkvT, CH, C3);
    transpose_cvt<<<dim3(CH / 32, CH / 32), 256, 0, stream>>>(Wproj, WprojT, CH, CH);
    transpose_cvt<<<dim3(DFF / 32, CH / 32), 256, 0, stream>>>(Wfc1, Wfc1T, CH, DFF);
    transpose_cvt<<<dim3(CH / 32, DFF / 32), 256, 0, stream>>>(Wfc2, Wfc2T, DFF, CH);
    // 3. qkv = x @ Wqkv + bqkv  (bf16 out)
    gemm_bt<1><<<dim3(C3 / 128, MROWS / 128), 256, 0, stream>>>(xb, WqkvT, bqkv, qkvb, MROWS, C3, CH);
    // 4. V transpose per head
    transpose_v<<<dim3(SEQ / 32, HD / 32, BB * NH), 256, 0, stream>>>(qkvb, vtb);
    // 5. attention
    attn_kernel<<<dim3(SEQ / 64, BB * NH), 256, 0, stream>>>(qkvb, vtb, attnb);
    // 6. proj (fp32 out)
    gemm_bt<0><<<dim3(CH / 128, MROWS / 128), 256, 0, stream>>>(attnb, WprojT, bproj, tmp, MROWS, CH, CH);
    // 7. LN1: y1 = LN(x + tmp)
    add_ln<<<MROWS, 256, 0, stream>>>(x, tmp, g1, b1, y1, y1b);
    // 8. fc1 + GELU (bf16 out)
    gemm_bt<2><<<dim3(DFF / 128, MROWS / 128), 256, 0, stream>>>(y1b, Wfc1T, bfc1, hb, MROWS, DFF, CH);
    // 9. fc2 (fp32 out)
    gemm_bt<0><<<dim3(CH / 128, MROWS / 128), 256, 0, stream>>>(hb, Wfc2T, bfc2, tmp, MROWS, CH, DFF);
    // 10. LN2 -> d_out
    add_ln<<<MROWS, 256, 0, stream>>>(y1, tmp, g2, b2, (float*)d_out, nullptr);
}

// Round 2
// 451.685 us; speedup vs baseline: 1.4249x; 1.4249x over previous
//
#include <hip/hip_runtime.h>

typedef __bf16 bf16;
typedef __bf16 bf16x2 __attribute__((ext_vector_type(2)));
typedef __bf16 bf16x4 __attribute__((ext_vector_type(4)));
typedef __bf16 bf16x8 __attribute__((ext_vector_type(8)));
typedef float  f32x4  __attribute__((ext_vector_type(4)));
typedef float  f32x16 __attribute__((ext_vector_type(16)));
typedef int    intx4  __attribute__((ext_vector_type(4)));

#define BB 4
#define SEQ 2048
#define CH 768
#define NH 12
#define HD 64
#define DFF 3072
#define MROWS (BB * SEQ)   // 8192
#define C3 (3 * CH)        // 2304

__device__ inline f32x16 mfma32(bf16x8 a, bf16x8 b, f32x16 c) {
    return __builtin_amdgcn_mfma_f32_32x32x16_bf16(a, b, c, 0, 0, 0);
}
__device__ inline f32x4 mfma16(bf16x8 a, bf16x8 b, f32x4 c) {
    return __builtin_amdgcn_mfma_f32_16x16x32_bf16(a, b, c, 0, 0, 0);
}
__device__ inline void gload16(const void* g, void* l) {
    __builtin_amdgcn_global_load_lds((const __attribute__((address_space(1))) void*)g,
                                     (__attribute__((address_space(3))) void*)l, 16, 0, 0);
}

// ---------------- fp32 -> bf16 convert (vectorized x4) ----------------
__global__ void cvt_f32_bf16(const float* __restrict__ in, bf16* __restrict__ out, int n) {
    int i = (blockIdx.x * blockDim.x + threadIdx.x) * 4;
    if (i + 3 >= n) {
        for (int j = 0; j < 4 && i + j < n; ++j) out[i + j] = (bf16)in[i + j];
        return;
    }
    f32x4 v = *(const f32x4*)&in[i];
    bf16x4 o;
    #pragma unroll
    for (int j = 0; j < 4; ++j) o[j] = (bf16)v[j];
    *(bf16x4*)&out[i] = o;
}

// ------------- transpose + convert: in fp32 [R, Cc] -> out bf16 [Cc, R] -------------
__global__ void transpose_cvt(const float* __restrict__ in, bf16* __restrict__ out, int R, int Cc) {
    __shared__ bf16 t[32][33];
    int tx = threadIdx.x & 31, ty = threadIdx.x >> 5;
    int c0 = blockIdx.x * 32, r0 = blockIdx.y * 32;
    #pragma unroll
    for (int i = 0; i < 32; i += 8)
        t[ty + i][tx] = (bf16)in[(size_t)(r0 + ty + i) * Cc + c0 + tx];
    __syncthreads();
    #pragma unroll
    for (int i = 0; i < 32; i += 8)
        out[(size_t)(c0 + ty + i) * R + r0 + tx] = t[tx][ty + i];
}

// ------------- V transpose: qkvb [B,S,3C] (V slice) -> vt [B*H, 64, S] -------------
__global__ void transpose_v(const bf16* __restrict__ qkvb, bf16* __restrict__ vt) {
    __shared__ bf16 t[32][33];
    int tx = threadIdx.x & 31, ty = threadIdx.x >> 5;
    int n0 = blockIdx.x * 32, d0 = blockIdx.y * 32, bh = blockIdx.z;
    int b = bh / NH, h = bh - b * NH;
    #pragma unroll
    for (int i = 0; i < 32; i += 8)
        t[ty + i][tx] = qkvb[((size_t)b * SEQ + n0 + ty + i) * C3 + 2 * CH + h * HD + d0 + tx];
    __syncthreads();
    #pragma unroll
    for (int i = 0; i < 32; i += 8)
        vt[((size_t)bh * HD + d0 + ty + i) * SEQ + n0 + tx] = t[tx][ty + i];
}

// ------------- GEMM (m97 structure): C[M,N] = A[M,K] * Bt[N,K]^T + bias -------------
// global_load_lds width-16 staging, linear LDS [128][32], 2-barrier K-loop.
// OMODE: 0 = fp32 out, 1 = bf16 out, 2 = bf16 out with exact GELU
template <int OMODE>
__global__ __launch_bounds__(256) void gemm_bt(const bf16* __restrict__ A,
                                               const bf16* __restrict__ Bt,
                                               const float* __restrict__ bias,
                                               void* __restrict__ Cout,
                                               int M, int N, int K) {
    __shared__ __align__(16) bf16 As[128][32];
    __shared__ __align__(16) bf16 Bs[128][32];
    const int bm = blockIdx.y * 128, bn = blockIdx.x * 128;
    const int tid = threadIdx.x;
    const int lane = tid & 63, w = tid >> 6;
    const int wr = w >> 1, wc = w & 1;
    const int lr = lane & 15, lg = lane >> 4;

    // staging addresses: unit u -> row u>>2, 16B-chunk u&3 (linear LDS per wave)
    const int srow = tid >> 2, schk = (tid & 3) * 8;
    const bf16* gA0 = A + (size_t)(bm + srow) * K + schk;
    const bf16* gA1 = A + (size_t)(bm + 64 + srow) * K + schk;
    const bf16* gB0 = Bt + (size_t)(bn + srow) * K + schk;
    const bf16* gB1 = Bt + (size_t)(bn + 64 + srow) * K + schk;
    bf16* lA0 = &As[srow][schk];
    bf16* lA1 = &As[64 + srow][schk];
    bf16* lB0 = &Bs[srow][schk];
    bf16* lB1 = &Bs[64 + srow][schk];

    f32x4 acc[4][4];
    #pragma unroll
    for (int i = 0; i < 4; ++i)
        #pragma unroll
        for (int j = 0; j < 4; ++j) acc[i][j] = (f32x4){0.f, 0.f, 0.f, 0.f};

    for (int k0 = 0; k0 < K; k0 += 32) {
        __syncthreads();
        gload16(gA0, lA0); gload16(gA1, lA1);
        gload16(gB0, lB0); gload16(gB1, lB1);
        gA0 += 32; gA1 += 32; gB0 += 32; gB1 += 32;
        __syncthreads();
        bf16x8 af[4], bfr[4];
        #pragma unroll
        for (int mi = 0; mi < 4; ++mi)
            af[mi] = *(const bf16x8*)&As[wr * 64 + mi * 16 + lr][lg * 8];
        #pragma unroll
        for (int ni = 0; ni < 4; ++ni)
            bfr[ni] = *(const bf16x8*)&Bs[wc * 64 + ni * 16 + lr][lg * 8];
        #pragma unroll
        for (int mi = 0; mi < 4; ++mi)
            #pragma unroll
            for (int ni = 0; ni < 4; ++ni)
                acc[mi][ni] = mfma16(af[mi], bfr[ni], acc[mi][ni]);
    }

    #pragma unroll
    for (int mi = 0; mi < 4; ++mi) {
        #pragma unroll
        for (int ni = 0; ni < 4; ++ni) {
            int col = bn + wc * 64 + ni * 16 + lr;
            float bsv = bias[col];
            #pragma unroll
            for (int r = 0; r < 4; ++r) {
                int row = bm + wr * 64 + mi * 16 + lg * 4 + r;
                float v = acc[mi][ni][r] + bsv;
                if (OMODE == 2) v = 0.5f * v * (1.0f + erff(v * 0.70710678118654752f));
                if (OMODE == 0)
                    ((float*)Cout)[(size_t)row * N + col] = v;
                else
                    ((bf16*)Cout)[(size_t)row * N + col] = (bf16)v;
            }
        }
    }
}

// ------------- flash attention, swapped-QK^T 32x32 structure -------------
// Each wave owns 32 q-rows; lane owns q-row (lane&31). St = mfma(K,Q) puts a
// half-row of kv scores per lane; softmax is in-lane + one shfl_xor(32).
// P repacked in-register (8 shfl_xor) into PV A-fragments. No LDS, no barriers.
__global__ __launch_bounds__(256) void attn_kernel(const bf16* __restrict__ qkvb,
                                                   const bf16* __restrict__ vt,
                                                   bf16* __restrict__ outb) {
    const int tid = threadIdx.x;
    const int w = tid >> 6, lane = tid & 63;
    const int lq = lane & 31;     // q-col within tile (and kv-row / d-col index)
    const int hi = lane >> 5;     // half-wave select
    // XCD-chunked bijective swizzle: 768 blocks = 8 XCDs x 96; 6 heads per XCD
    const int lin = blockIdx.x;
    const int xcd = lin & 7, slot = lin >> 3;
    const int bh = xcd * 6 + (slot >> 4);
    const int qt = slot & 15;
    const int b = bh / NH, h = bh - b * NH;
    const int q0 = qt * 128 + w * 32;

    const bf16* qbase = qkvb + (size_t)b * SEQ * C3 + h * HD;
    const bf16* kbase = qbase + CH;
    const bf16* vbase = vt + (size_t)bh * HD * SEQ;

    bf16x8 qf[4];
    #pragma unroll
    for (int ks = 0; ks < 4; ++ks)
        qf[ks] = *(const bf16x8*)&qbase[(size_t)(q0 + lq) * C3 + ks * 16 + hi * 8];

    f32x16 o0 = {0.f}, o1 = {0.f};
    float m = -3.0e38f, l = 0.f;

    for (int kv = 0; kv < SEQ; kv += 32) {
        // ---- QK^T (swapped): St[kv-rows][q-cols] ----
        f32x16 st = {0.f};
        #pragma unroll
        for (int ks = 0; ks < 4; ++ks) {
            bf16x8 kf = *(const bf16x8*)&kbase[(size_t)(kv + lq) * C3 + ks * 16 + hi * 8];
            st = mfma32(kf, qf[ks], st);
        }
        // ---- row max (raw domain), tree + one cross-half shuffle ----
        float t0[8], t1[4];
        #pragma unroll
        for (int r = 0; r < 8; ++r) t0[r] = fmaxf(st[r], st[r + 8]);
        #pragma unroll
        for (int r = 0; r < 4; ++r) t1[r] = fmaxf(t0[r], t0[r + 4]);
        float mx = fmaxf(fmaxf(t1[0], t1[1]), fmaxf(t1[2], t1[3]));
        mx = fmaxf(mx, __shfl_xor(mx, 32));
        float mxs = mx * 0.125f;
        // ---- defer-max (T13, THR=8): rescale only when max grows past slack ----
        if (!__all(mxs <= m + 8.0f)) {
            float mn = fmaxf(m, mxs);
            float alpha = __expf(m - mn);
            m = mn;
            l *= alpha;
            #pragma unroll
            for (int r = 0; r < 16; ++r) {
                int qr = (r & 3) + 8 * (r >> 2) + 4 * hi;
                float ar = __shfl(alpha, qr);
                o0[r] *= ar;
                o1[r] *= ar;
            }
        }
        // ---- P = exp(s*scale - m), row-sum ----
        float p[16];
        #pragma unroll
        for (int r = 0; r < 16; ++r) p[r] = __expf(fmaf(st[r], 0.125f, -m));
        float s0[8], s1[4];
        #pragma unroll
        for (int r = 0; r < 8; ++r) s0[r] = p[r] + p[r + 8];
        #pragma unroll
        for (int r = 0; r < 4; ++r) s1[r] = s0[r] + s0[r + 4];
        float ps = (s1[0] + s1[1]) + (s1[2] + s1[3]);
        ps += __shfl_xor(ps, 32);
        l += ps;
        // ---- pack P to bf16 pairs, cross-half exchange -> PV A-fragments ----
        int a[8];
        #pragma unroll
        for (int i = 0; i < 8; ++i) {
            bf16x2 t2 = {(bf16)p[2 * i], (bf16)p[2 * i + 1]};
            a[i] = __builtin_bit_cast(int, t2);
        }
        int bs[8];
        #pragma unroll
        for (int i = 0; i < 8; ++i) bs[i] = __shfl_xor(a[i], 32);
        intx4 f0 = hi ? (intx4){bs[2], bs[3], a[2], a[3]} : (intx4){a[0], a[1], bs[0], bs[1]};
        intx4 f1 = hi ? (intx4){bs[6], bs[7], a[6], a[7]} : (intx4){a[4], a[5], bs[4], bs[5]};
        bf16x8 pa0 = __builtin_bit_cast(bf16x8, f0);
        bf16x8 pa1 = __builtin_bit_cast(bf16x8, f1);
        // ---- PV: O[q][d] += P[q][kv] * Vt[d][kv]^T ----
        const bf16* vr0 = &vbase[(size_t)lq * SEQ + kv];
        const bf16* vr1 = &vbase[(size_t)(32 + lq) * SEQ + kv];
        o0 = mfma32(pa0, *(const bf16x8*)&vr0[hi * 8], o0);
        o0 = mfma32(pa1, *(const bf16x8*)&vr0[16 + hi * 8], o0);
        o1 = mfma32(pa0, *(const bf16x8*)&vr1[hi * 8], o1);
        o1 = mfma32(pa1, *(const bf16x8*)&vr1[16 + hi * 8], o1);
    }

    float linv = 1.0f / l;
    const size_t obase = (size_t)b * SEQ * CH + h * HD;
    #pragma unroll
    for (int r = 0; r < 16; ++r) {
        int qr = (r & 3) + 8 * (r >> 2) + 4 * hi;
        float lr_ = __shfl(linv, qr);
        size_t rowo = obase + (size_t)(q0 + qr) * CH;
        outb[rowo + lq] = (bf16)(o0[r] * lr_);
        outb[rowo + 32 + lq] = (bf16)(o1[r] * lr_);
    }
}

// ------------- fused residual add + LayerNorm -------------
__global__ __launch_bounds__(256) void add_ln(const float* __restrict__ x,
                                              const float* __restrict__ t,
                                              const float* __restrict__ g,
                                              const float* __restrict__ bt,
                                              float* __restrict__ y,
                                              bf16* __restrict__ yb) {
    const int row = blockIdx.x;
    const size_t base = (size_t)row * CH;
    const int tid = threadIdx.x;
    float v[3];
    #pragma unroll
    for (int k = 0; k < 3; ++k) {
        int c = tid + k * 256;
        v[k] = x[base + c] + t[base + c];
    }
    __shared__ float red[4];
    float s = v[0] + v[1] + v[2];
    #pragma unroll
    for (int off = 32; off >= 1; off >>= 1) s += __shfl_down(s, off);
    if ((tid & 63) == 0) red[tid >> 6] = s;
    __syncthreads();
    float mean = (red[0] + red[1] + red[2] + red[3]) * (1.0f / 768.0f);
    float q = 0.f;
    #pragma unroll
    for (int k = 0; k < 3; ++k) {
        float d = v[k] - mean;
        q += d * d;
    }
    __syncthreads();
    #pragma unroll
    for (int off = 32; off >= 1; off >>= 1) q += __shfl_down(q, off);
    if ((tid & 63) == 0) red[tid >> 6] = q;
    __syncthreads();
    float var = (red[0] + red[1] + red[2] + red[3]) * (1.0f / 768.0f);
    float rstd = rsqrtf(var + 1e-5f);
    #pragma unroll
    for (int k = 0; k < 3; ++k) {
        int c = tid + k * 256;
        float out = (v[k] - mean) * rstd * g[c] + bt[c];
        y[base + c] = out;
        if (yb) yb[base + c] = (bf16)out;
    }
}

extern "C" void kernel_launch(void* const* d_in, const int* in_sizes, int n_in,
                              void* d_out, int out_size, void* d_ws, size_t ws_size,
                              hipStream_t stream) {
    const float* x    = (const float*)d_in[0];
    const float* Wqkv = (const float*)d_in[1];
    const float* bqkv = (const float*)d_in[2];
    const float* Wproj= (const float*)d_in[3];
    const float* bproj= (const float*)d_in[4];
    const float* g1   = (const float*)d_in[5];
    const float* b1   = (const float*)d_in[6];
    const float* g2   = (const float*)d_in[7];
    const float* b2   = (const float*)d_in[8];
    const float* Wfc1 = (const float*)d_in[9];
    const float* bfc1 = (const float*)d_in[10];
    const float* Wfc2 = (const float*)d_in[11];
    const float* bfc2 = (const float*)d_in[12];

    char* ws = (char*)d_ws;
    size_t off = 0;
    auto alloc = [&](size_t bytes) -> void* {
        void* p = ws + off;
        off += (bytes + 255) & ~(size_t)255;
        return p;
    };

    bf16* xb     = (bf16*)alloc((size_t)MROWS * CH * 2);
    bf16* WqkvT  = (bf16*)alloc((size_t)C3 * CH * 2);
    bf16* WprojT = (bf16*)alloc((size_t)CH * CH * 2);
    bf16* Wfc1T  = (bf16*)alloc((size_t)DFF * CH * 2);
    bf16* Wfc2T  = (bf16*)alloc((size_t)CH * DFF * 2);
    bf16* qkvb   = (bf16*)alloc((size_t)MROWS * C3 * 2);
    bf16* vtb    = (bf16*)alloc((size_t)BB * NH * HD * SEQ * 2);
    bf16* attnb  = (bf16*)alloc((size_t)MROWS * CH * 2);
    float* tmp   = (float*)alloc((size_t)MROWS * CH * 4);
    float* y1    = (float*)alloc((size_t)MROWS * CH * 4);
    bf16* y1b    = (bf16*)alloc((size_t)MROWS * CH * 2);
    bf16* hb     = (bf16*)alloc((size_t)MROWS * DFF * 2);

    // 1. x -> bf16
    cvt_f32_bf16<<<(MROWS * CH / 4 + 255) / 256, 256, 0, stream>>>(x, xb, MROWS * CH);
    // 2. weight transposes (fp32 [K,N] -> bf16 [N,K])
    transpose_cvt<<<dim3(C3 / 32, CH / 32), 256, 0, stream>>>(Wqkv, WqkvT, CH, C3);
    transpose_cvt<<<dim3(CH / 32, CH / 32), 256, 0, stream>>>(Wproj, WprojT, CH, CH);
    transpose_cvt<<<dim3(DFF / 32, CH / 32), 256, 0, stream>>>(Wfc1, Wfc1T, CH, DFF);
    transpose_cvt<<<dim3(CH / 32, DFF / 32), 256, 0, stream>>>(Wfc2, Wfc2T, DFF, CH);
    // 3. qkv = x @ Wqkv + bqkv  (bf16 out)
    gemm_bt<1><<<dim3(C3 / 128, MROWS / 128), 256, 0, stream>>>(xb, WqkvT, bqkv, qkvb, MROWS, C3, CH);
    // 4. V transpose per head
    transpose_v<<<dim3(SEQ / 32, HD / 32, BB * NH), 256, 0, stream>>>(qkvb, vtb);
    // 5. attention (768 blocks = 8 XCD chunks of 96)
    attn_kernel<<<768, 256, 0, stream>>>(qkvb, vtb, attnb);
    // 6. proj (fp32 out)
    gemm_bt<0><<<dim3(CH / 128, MROWS / 128), 256, 0, stream>>>(attnb, WprojT, bproj, tmp, MROWS, CH, CH);
    // 7. LN1: y1 = LN(x + tmp)
    add_ln<<<MROWS, 256, 0, stream>>>(x, tmp, g1, b1, y1, y1b);
    // 8. fc1 + GELU (bf16 out)
    gemm_bt<2><<<dim3(DFF / 128, MROWS / 128), 256, 0, stream>>>(y1b, Wfc1T, bfc1, hb, MROWS, DFF, CH);
    // 9. fc2 (fp32 out)
    gemm_bt<0><<<dim3(CH / 128, MROWS / 128), 256, 0, stream>>>(hb, Wfc2T, bfc2, tmp, MROWS, CH, DFF);
    // 10. LN2 -> d_out
    add_ln<<<MROWS, 256, 0, stream>>>(y1, tmp, g2, b2, (float*)d_out, nullptr);
}

// Round 3
// 451.037 us; speedup vs baseline: 1.4269x; 1.0014x over previous
//
#include <hip/hip_runtime.h>

typedef __bf16 bf16;
typedef __bf16 bf16x2 __attribute__((ext_vector_type(2)));
typedef __bf16 bf16x4 __attribute__((ext_vector_type(4)));
typedef __bf16 bf16x8 __attribute__((ext_vector_type(8)));
typedef float  f32x4  __attribute__((ext_vector_type(4)));
typedef float  f32x16 __attribute__((ext_vector_type(16)));
typedef int    intx4  __attribute__((ext_vector_type(4)));

#define BB 4
#define SEQ 2048
#define CH 768
#define NH 12
#define HD 64
#define DFF 3072
#define MROWS (BB * SEQ)   // 8192
#define C3 (3 * CH)        // 2304

__device__ inline f32x16 mfma32(bf16x8 a, bf16x8 b, f32x16 c) {
    return __builtin_amdgcn_mfma_f32_32x32x16_bf16(a, b, c, 0, 0, 0);
}
__device__ inline f32x4 mfma16(bf16x8 a, bf16x8 b, f32x4 c) {
    return __builtin_amdgcn_mfma_f32_16x16x32_bf16(a, b, c, 0, 0, 0);
}
__device__ inline void gload16(const void* g, void* l) {
    __builtin_amdgcn_global_load_lds((const __attribute__((address_space(1))) void*)g,
                                     (__attribute__((address_space(3))) void*)l, 16, 0, 0);
}

// ---------------- fp32 -> bf16 convert (vectorized x4) ----------------
__global__ void cvt_f32_bf16(const float* __restrict__ in, bf16* __restrict__ out, int n) {
    int i = (blockIdx.x * blockDim.x + threadIdx.x) * 4;
    if (i + 3 >= n) {
        for (int j = 0; j < 4 && i + j < n; ++j) out[i + j] = (bf16)in[i + j];
        return;
    }
    f32x4 v = *(const f32x4*)&in[i];
    bf16x4 o;
    #pragma unroll
    for (int j = 0; j < 4; ++j) o[j] = (bf16)v[j];
    *(bf16x4*)&out[i] = o;
}

// ------------- transpose + convert: in fp32 [R, Cc] -> out bf16 [Cc, R] -------------
__global__ void transpose_cvt(const float* __restrict__ in, bf16* __restrict__ out, int R, int Cc) {
    __shared__ bf16 t[32][33];
    int tx = threadIdx.x & 31, ty = threadIdx.x >> 5;
    int c0 = blockIdx.x * 32, r0 = blockIdx.y * 32;
    #pragma unroll
    for (int i = 0; i < 32; i += 8)
        t[ty + i][tx] = (bf16)in[(size_t)(r0 + ty + i) * Cc + c0 + tx];
    __syncthreads();
    #pragma unroll
    for (int i = 0; i < 32; i += 8)
        out[(size_t)(c0 + ty + i) * R + r0 + tx] = t[tx][ty + i];
}

// ------------- V transpose: qkvb [B,S,3C] (V slice) -> vt [B*H, 64, S] -------------
__global__ void transpose_v(const bf16* __restrict__ qkvb, bf16* __restrict__ vt) {
    __shared__ bf16 t[32][33];
    int tx = threadIdx.x & 31, ty = threadIdx.x >> 5;
    int n0 = blockIdx.x * 32, d0 = blockIdx.y * 32, bh = blockIdx.z;
    int b = bh / NH, h = bh - b * NH;
    #pragma unroll
    for (int i = 0; i < 32; i += 8)
        t[ty + i][tx] = qkvb[((size_t)b * SEQ + n0 + ty + i) * C3 + 2 * CH + h * HD + d0 + tx];
    __syncthreads();
    #pragma unroll
    for (int i = 0; i < 32; i += 8)
        vt[((size_t)bh * HD + d0 + ty + i) * SEQ + n0 + tx] = t[tx][ty + i];
}

// ------------- GEMM (m97 structure): C[M,N] = A[M,K] * Bt[N,K]^T + bias -------------
template <int OMODE>
__global__ __launch_bounds__(256) void gemm_bt(const bf16* __restrict__ A,
                                               const bf16* __restrict__ Bt,
                                               const float* __restrict__ bias,
                                               void* __restrict__ Cout,
                                               int M, int N, int K) {
    __shared__ __align__(16) bf16 As[128][32];
    __shared__ __align__(16) bf16 Bs[128][32];
    const int bm = blockIdx.y * 128, bn = blockIdx.x * 128;
    const int tid = threadIdx.x;
    const int lane = tid & 63, w = tid >> 6;
    const int wr = w >> 1, wc = w & 1;
    const int lr = lane & 15, lg = lane >> 4;

    const int srow = tid >> 2, schk = (tid & 3) * 8;
    const bf16* gA0 = A + (size_t)(bm + srow) * K + schk;
    const bf16* gA1 = A + (size_t)(bm + 64 + srow) * K + schk;
    const bf16* gB0 = Bt + (size_t)(bn + srow) * K + schk;
    const bf16* gB1 = Bt + (size_t)(bn + 64 + srow) * K + schk;
    bf16* lA0 = &As[srow][schk];
    bf16* lA1 = &As[64 + srow][schk];
    bf16* lB0 = &Bs[srow][schk];
    bf16* lB1 = &Bs[64 + srow][schk];

    f32x4 acc[4][4];
    #pragma unroll
    for (int i = 0; i < 4; ++i)
        #pragma unroll
        for (int j = 0; j < 4; ++j) acc[i][j] = (f32x4){0.f, 0.f, 0.f, 0.f};

    for (int k0 = 0; k0 < K; k0 += 32) {
        __syncthreads();
        gload16(gA0, lA0); gload16(gA1, lA1);
        gload16(gB0, lB0); gload16(gB1, lB1);
        gA0 += 32; gA1 += 32; gB0 += 32; gB1 += 32;
        __syncthreads();
        bf16x8 af[4], bfr[4];
        #pragma unroll
        for (int mi = 0; mi < 4; ++mi)
            af[mi] = *(const bf16x8*)&As[wr * 64 + mi * 16 + lr][lg * 8];
        #pragma unroll
        for (int ni = 0; ni < 4; ++ni)
            bfr[ni] = *(const bf16x8*)&Bs[wc * 64 + ni * 16 + lr][lg * 8];
        #pragma unroll
        for (int mi = 0; mi < 4; ++mi)
            #pragma unroll
            for (int ni = 0; ni < 4; ++ni)
                acc[mi][ni] = mfma16(af[mi], bfr[ni], acc[mi][ni]);
    }

    #pragma unroll
    for (int mi = 0; mi < 4; ++mi) {
        #pragma unroll
        for (int ni = 0; ni < 4; ++ni) {
            int col = bn + wc * 64 + ni * 16 + lr;
            float bsv = bias[col];
            #pragma unroll
            for (int r = 0; r < 4; ++r) {
                int row = bm + wr * 64 + mi * 16 + lg * 4 + r;
                float v = acc[mi][ni][r] + bsv;
                if (OMODE == 2) v = 0.5f * v * (1.0f + erff(v * 0.70710678118654752f));
                if (OMODE == 0)
                    ((float*)Cout)[(size_t)row * N + col] = v;
                else
                    ((bf16*)Cout)[(size_t)row * N + col] = (bf16)v;
            }
        }
    }
}

// ------------- flash attention, swapped-QK^T 32x32, prefetched -------------
// exp2-domain softmax; K(t+1)/V(t) loads pipelined under compute; 6 cross-lane
// ops per kv-tile (4 pack exchanges + max + sum).
#define C2F 0.18033688011112f   /* 0.125 * log2(e) */
#define THR2 11.5416f           /* 8 * log2(e) */
__global__ __launch_bounds__(256, 3) void attn_kernel(const bf16* __restrict__ qkvb,
                                                      const bf16* __restrict__ vt,
                                                      bf16* __restrict__ outb) {
    const int tid = threadIdx.x;
    const int w = tid >> 6, lane = tid & 63;
    const int lq = lane & 31;
    const int hi = lane >> 5;
    const int lin = blockIdx.x;
    const int xcd = lin & 7, slot = lin >> 3;
    const int bh = xcd * 6 + (slot >> 4);
    const int qt = slot & 15;
    const int b = bh / NH, h = bh - b * NH;
    const int q0 = qt * 128 + w * 32;

    const bf16* qbase = qkvb + (size_t)b * SEQ * C3 + h * HD;
    const bf16* kbase = qbase + CH;
    const bf16* vbase = vt + (size_t)bh * HD * SEQ;
    const bf16* vr0 = &vbase[(size_t)lq * SEQ];
    const bf16* vr1 = &vbase[(size_t)(32 + lq) * SEQ];

    bf16x8 qf[4];
    #pragma unroll
    for (int ks = 0; ks < 4; ++ks)
        qf[ks] = *(const bf16x8*)&qbase[(size_t)(q0 + lq) * C3 + ks * 16 + hi * 8];

    // preload K tile 0
    bf16x8 kf[4];
    #pragma unroll
    for (int ks = 0; ks < 4; ++ks)
        kf[ks] = *(const bf16x8*)&kbase[(size_t)lq * C3 + ks * 16 + hi * 8];

    f32x16 o0 = {0.f}, o1 = {0.f};
    float m = -3.0e38f, l = 0.f;

    for (int kv = 0; kv < SEQ; kv += 32) {
        // ---- issue V(t) loads (consumed by PV at tile end) ----
        bf16x8 vf0 = *(const bf16x8*)&vr0[kv + hi * 8];
        bf16x8 vf1 = *(const bf16x8*)&vr0[kv + 16 + hi * 8];
        bf16x8 vf2 = *(const bf16x8*)&vr1[kv + hi * 8];
        bf16x8 vf3 = *(const bf16x8*)&vr1[kv + 16 + hi * 8];
        // ---- QK^T (swapped): St[kv-rows][q-cols] ----
        f32x16 st = {0.f};
        st = mfma32(kf[0], qf[0], st);
        st = mfma32(kf[1], qf[1], st);
        st = mfma32(kf[2], qf[2], st);
        st = mfma32(kf[3], qf[3], st);
        // ---- issue K(t+1) loads (wrap on last iter; value unused) ----
        const int kvn = (kv + 32) & (SEQ - 1);
        bf16x8 kn[4];
        #pragma unroll
        for (int ks = 0; ks < 4; ++ks)
            kn[ks] = *(const bf16x8*)&kbase[(size_t)(kvn + lq) * C3 + ks * 16 + hi * 8];
        // ---- row max (raw domain) ----
        float t0[8], t1[4];
        #pragma unroll
        for (int r = 0; r < 8; ++r) t0[r] = fmaxf(st[r], st[r + 8]);
        #pragma unroll
        for (int r = 0; r < 4; ++r) t1[r] = fmaxf(t0[r], t0[r + 4]);
        float mx = fmaxf(fmaxf(t1[0], t1[1]), fmaxf(t1[2], t1[3]));
        mx = fmaxf(mx, __shfl_xor(mx, 32));
        float m2x = mx * C2F;
        // ---- defer-max rescale (exp2 domain) ----
        if (!__all(m2x <= m + THR2)) {
            float mn = fmaxf(m, m2x);
            float alpha = __builtin_amdgcn_exp2f(m - mn);
            m = mn;
            l *= alpha;
            #pragma unroll
            for (int r = 0; r < 16; ++r) {
                int qr = (r & 3) + 8 * (r >> 2) + 4 * hi;
                float ar = __shfl(alpha, qr);
                o0[r] *= ar;
                o1[r] *= ar;
            }
        }
        // ---- P = exp2(st*C2 - m), row-sum ----
        float p[16];
        #pragma unroll
        for (int r = 0; r < 16; ++r) p[r] = __builtin_amdgcn_exp2f(fmaf(st[r], C2F, -m));
        float s0[8], s1[4];
        #pragma unroll
        for (int r = 0; r < 8; ++r) s0[r] = p[r] + p[r + 8];
        #pragma unroll
        for (int r = 0; r < 4; ++r) s1[r] = s0[r] + s0[r + 4];
        float ps = (s1[0] + s1[1]) + (s1[2] + s1[3]);
        ps += __shfl_xor(ps, 32);
        l += ps;
        // ---- pack P to bf16 pairs; 4 cross-half exchanges -> PV A-frags ----
        int a[8];
        #pragma unroll
        for (int i = 0; i < 8; ++i) {
            bf16x2 t2 = {(bf16)p[2 * i], (bf16)p[2 * i + 1]};
            a[i] = __builtin_bit_cast(int, t2);
        }
        int d0 = __shfl_xor(hi ? a[0] : a[2], 32);
        int d1 = __shfl_xor(hi ? a[1] : a[3], 32);
        int d2 = __shfl_xor(hi ? a[4] : a[6], 32);
        int d3 = __shfl_xor(hi ? a[5] : a[7], 32);
        intx4 f0 = hi ? (intx4){d0, d1, a[2], a[3]} : (intx4){a[0], a[1], d0, d1};
        intx4 f1 = hi ? (intx4){d2, d3, a[6], a[7]} : (intx4){a[4], a[5], d2, d3};
        bf16x8 pa0 = __builtin_bit_cast(bf16x8, f0);
        bf16x8 pa1 = __builtin_bit_cast(bf16x8, f1);
        // ---- PV ----
        o0 = mfma32(pa0, vf0, o0);
        o0 = mfma32(pa1, vf1, o0);
        o1 = mfma32(pa0, vf2, o1);
        o1 = mfma32(pa1, vf3, o1);
        // ---- rotate K ----
        kf[0] = kn[0]; kf[1] = kn[1]; kf[2] = kn[2]; kf[3] = kn[3];
    }

    float linv = 1.0f / l;
    const size_t obase = (size_t)b * SEQ * CH + h * HD;
    #pragma unroll
    for (int r = 0; r < 16; ++r) {
        int qr = (r & 3) + 8 * (r >> 2) + 4 * hi;
        float lr_ = __shfl(linv, qr);
        size_t rowo = obase + (size_t)(q0 + qr) * CH;
        outb[rowo + lq] = (bf16)(o0[r] * lr_);
        outb[rowo + 32 + lq] = (bf16)(o1[r] * lr_);
    }
}

// ------------- fused residual add + LayerNorm -------------
__global__ __launch_bounds__(256) void add_ln(const float* __restrict__ x,
                                              const float* __restrict__ t,
                                              const float* __restrict__ g,
                                              const float* __restrict__ bt,
                                              float* __restrict__ y,
                                              bf16* __restrict__ yb) {
    const int row = blockIdx.x;
    const size_t base = (size_t)row * CH;
    const int tid = threadIdx.x;
    float v[3];
    #pragma unroll
    for (int k = 0; k < 3; ++k) {
        int c = tid + k * 256;
        v[k] = x[base + c] + t[base + c];
    }
    __shared__ float red[4];
    float s = v[0] + v[1] + v[2];
    #pragma unroll
    for (int off = 32; off >= 1; off >>= 1) s += __shfl_down(s, off);
    if ((tid & 63) == 0) red[tid >> 6] = s;
    __syncthreads();
    float mean = (red[0] + red[1] + red[2] + red[3]) * (1.0f / 768.0f);
    float q = 0.f;
    #pragma unroll
    for (int k = 0; k < 3; ++k) {
        float d = v[k] - mean;
        q += d * d;
    }
    __syncthreads();
    #pragma unroll
    for (int off = 32; off >= 1; off >>= 1) q += __shfl_down(q, off);
    if ((tid & 63) == 0) red[tid >> 6] = q;
    __syncthreads();
    float var = (red[0] + red[1] + red[2] + red[3]) * (1.0f / 768.0f);
    float rstd = rsqrtf(var + 1e-5f);
    #pragma unroll
    for (int k = 0; k < 3; ++k) {
        int c = tid + k * 256;
        float out = (v[k] - mean) * rstd * g[c] + bt[c];
        y[base + c] = out;
        if (yb) yb[base + c] = (bf16)out;
    }
}

extern "C" void kernel_launch(void* const* d_in, const int* in_sizes, int n_in,
                              void* d_out, int out_size, void* d_ws, size_t ws_size,
                              hipStream_t stream) {
    const float* x    = (const float*)d_in[0];
    const float* Wqkv = (const float*)d_in[1];
    const float* bqkv = (const float*)d_in[2];
    const float* Wproj= (const float*)d_in[3];
    const float* bproj= (const float*)d_in[4];
    const float* g1   = (const float*)d_in[5];
    const float* b1   = (const float*)d_in[6];
    const float* g2   = (const float*)d_in[7];
    const float* b2   = (const float*)d_in[8];
    const float* Wfc1 = (const float*)d_in[9];
    const float* bfc1 = (const float*)d_in[10];
    const float* Wfc2 = (const float*)d_in[11];
    const float* bfc2 = (const float*)d_in[12];

    char* ws = (char*)d_ws;
    size_t off = 0;
    auto alloc = [&](size_t bytes) -> void* {
        void* p = ws + off;
        off += (bytes + 255) & ~(size_t)255;
        return p;
    };

    bf16* xb     = (bf16*)alloc((size_t)MROWS * CH * 2);
    bf16* WqkvT  = (bf16*)alloc((size_t)C3 * CH * 2);
    bf16* WprojT = (bf16*)alloc((size_t)CH * CH * 2);
    bf16* Wfc1T  = (bf16*)alloc((size_t)DFF * CH * 2);
    bf16* Wfc2T  = (bf16*)alloc((size_t)CH * DFF * 2);
    bf16* qkvb   = (bf16*)alloc((size_t)MROWS * C3 * 2);
    bf16* vtb    = (bf16*)alloc((size_t)BB * NH * HD * SEQ * 2);
    bf16* attnb  = (bf16*)alloc((size_t)MROWS * CH * 2);
    float* tmp   = (float*)alloc((size_t)MROWS * CH * 4);
    float* y1    = (float*)alloc((size_t)MROWS * CH * 4);
    bf16* y1b    = (bf16*)alloc((size_t)MROWS * CH * 2);
    bf16* hb     = (bf16*)alloc((size_t)MROWS * DFF * 2);

    cvt_f32_bf16<<<(MROWS * CH / 4 + 255) / 256, 256, 0, stream>>>(x, xb, MROWS * CH);
    transpose_cvt<<<dim3(C3 / 32, CH / 32), 256, 0, stream>>>(Wqkv, WqkvT, CH, C3);
    transpose_cvt<<<dim3(CH / 32, CH / 32), 256, 0, stream>>>(Wproj, WprojT, CH, CH);
    transpose_cvt<<<dim3(DFF / 32, CH / 32), 256, 0, stream>>>(Wfc1, Wfc1T, CH, DFF);
    transpose_cvt<<<dim3(CH / 32, DFF / 32), 256, 0, stream>>>(Wfc2, Wfc2T, DFF, CH);
    gemm_bt<1><<<dim3(C3 / 128, MROWS / 128), 256, 0, stream>>>(xb, WqkvT, bqkv, qkvb, MROWS, C3, CH);
    transpose_v<<<dim3(SEQ / 32, HD / 32, BB * NH), 256, 0, stream>>>(qkvb, vtb);
    attn_kernel<<<768, 256, 0, stream>>>(qkvb, vtb, attnb);
    gemm_bt<0><<<dim3(CH / 128, MROWS / 128), 256, 0, stream>>>(attnb, WprojT, bproj, tmp, MROWS, CH, CH);
    add_ln<<<MROWS, 256, 0, stream>>>(x, tmp, g1, b1, y1, y1b);
    gemm_bt<2><<<dim3(DFF / 128, MROWS / 128), 256, 0, stream>>>(y1b, Wfc1T, bfc1, hb, MROWS, DFF, CH);
    gemm_bt<0><<<dim3(CH / 128, MROWS / 128), 256, 0, stream>>>(hb, Wfc2T, bfc2, tmp, MROWS, CH, DFF);
    add_ln<<<MROWS, 256, 0, stream>>>(y1, tmp, g2, b2, (float*)d_out, nullptr);
}

// Round 4
// 353.426 us; speedup vs baseline: 1.8210x; 1.2762x over previous
//
#include <hip/hip_runtime.h>

typedef __bf16 bf16;
typedef __bf16 bf16x2 __attribute__((ext_vector_type(2)));
typedef __bf16 bf16x4 __attribute__((ext_vector_type(4)));
typedef __bf16 bf16x8 __attribute__((ext_vector_type(8)));
typedef float  f32x4  __attribute__((ext_vector_type(4)));
typedef float  f32x16 __attribute__((ext_vector_type(16)));
typedef int    intx4  __attribute__((ext_vector_type(4)));

#define BB 4
#define SEQ 2048
#define CH 768
#define NH 12
#define HD 64
#define DFF 3072
#define MROWS (BB * SEQ)   // 8192
#define C3 (3 * CH)        // 2304

__device__ inline f32x16 mfma32(bf16x8 a, bf16x8 b, f32x16 c) {
    return __builtin_amdgcn_mfma_f32_32x32x16_bf16(a, b, c, 0, 0, 0);
}
__device__ inline f32x4 mfma16(bf16x8 a, bf16x8 b, f32x4 c) {
    return __builtin_amdgcn_mfma_f32_16x16x32_bf16(a, b, c, 0, 0, 0);
}
__device__ inline void gload16(const void* g, void* l) {
    __builtin_amdgcn_global_load_lds((const __attribute__((address_space(1))) void*)g,
                                     (__attribute__((address_space(3))) void*)l, 16, 0, 0);
}

// ---------------- fp32 -> bf16 convert (vectorized x4) ----------------
__global__ void cvt_f32_bf16(const float* __restrict__ in, bf16* __restrict__ out, int n) {
    int i = (blockIdx.x * blockDim.x + threadIdx.x) * 4;
    if (i + 3 >= n) {
        for (int j = 0; j < 4 && i + j < n; ++j) out[i + j] = (bf16)in[i + j];
        return;
    }
    f32x4 v = *(const f32x4*)&in[i];
    bf16x4 o;
    #pragma unroll
    for (int j = 0; j < 4; ++j) o[j] = (bf16)v[j];
    *(bf16x4*)&out[i] = o;
}

// ------------- transpose + convert: in fp32 [R, Cc] -> out bf16 [Cc, R] -------------
__global__ void transpose_cvt(const float* __restrict__ in, bf16* __restrict__ out, int R, int Cc) {
    __shared__ bf16 t[32][33];
    int tx = threadIdx.x & 31, ty = threadIdx.x >> 5;
    int c0 = blockIdx.x * 32, r0 = blockIdx.y * 32;
    #pragma unroll
    for (int i = 0; i < 32; i += 8)
        t[ty + i][tx] = (bf16)in[(size_t)(r0 + ty + i) * Cc + c0 + tx];
    __syncthreads();
    #pragma unroll
    for (int i = 0; i < 32; i += 8)
        out[(size_t)(c0 + ty + i) * R + r0 + tx] = t[tx][ty + i];
}

// ------------- V transpose: qkvb [B,S,3C] (V slice) -> vt [B*H, 64, S] -------------
__global__ void transpose_v(const bf16* __restrict__ qkvb, bf16* __restrict__ vt) {
    __shared__ bf16 t[32][33];
    int tx = threadIdx.x & 31, ty = threadIdx.x >> 5;
    int n0 = blockIdx.x * 32, d0 = blockIdx.y * 32, bh = blockIdx.z;
    int b = bh / NH, h = bh - b * NH;
    #pragma unroll
    for (int i = 0; i < 32; i += 8)
        t[ty + i][tx] = qkvb[((size_t)b * SEQ + n0 + ty + i) * C3 + 2 * CH + h * HD + d0 + tx];
    __syncthreads();
    #pragma unroll
    for (int i = 0; i < 32; i += 8)
        vt[((size_t)bh * HD + d0 + ty + i) * SEQ + n0 + tx] = t[tx][ty + i];
}

// ------------- GEMM (m97 structure): C[M,N] = A[M,K] * Bt[N,K]^T + bias -------------
template <int OMODE>
__global__ __launch_bounds__(256) void gemm_bt(const bf16* __restrict__ A,
                                               const bf16* __restrict__ Bt,
                                               const float* __restrict__ bias,
                                               void* __restrict__ Cout,
                                               int M, int N, int K) {
    __shared__ __align__(16) bf16 As[128][32];
    __shared__ __align__(16) bf16 Bs[128][32];
    const int bm = blockIdx.y * 128, bn = blockIdx.x * 128;
    const int tid = threadIdx.x;
    const int lane = tid & 63, w = tid >> 6;
    const int wr = w >> 1, wc = w & 1;
    const int lr = lane & 15, lg = lane >> 4;

    const int srow = tid >> 2, schk = (tid & 3) * 8;
    const bf16* gA0 = A + (size_t)(bm + srow) * K + schk;
    const bf16* gA1 = A + (size_t)(bm + 64 + srow) * K + schk;
    const bf16* gB0 = Bt + (size_t)(bn + srow) * K + schk;
    const bf16* gB1 = Bt + (size_t)(bn + 64 + srow) * K + schk;
    bf16* lA0 = &As[srow][schk];
    bf16* lA1 = &As[64 + srow][schk];
    bf16* lB0 = &Bs[srow][schk];
    bf16* lB1 = &Bs[64 + srow][schk];

    f32x4 acc[4][4];
    #pragma unroll
    for (int i = 0; i < 4; ++i)
        #pragma unroll
        for (int j = 0; j < 4; ++j) acc[i][j] = (f32x4){0.f, 0.f, 0.f, 0.f};

    for (int k0 = 0; k0 < K; k0 += 32) {
        __syncthreads();
        gload16(gA0, lA0); gload16(gA1, lA1);
        gload16(gB0, lB0); gload16(gB1, lB1);
        gA0 += 32; gA1 += 32; gB0 += 32; gB1 += 32;
        __syncthreads();
        bf16x8 af[4], bfr[4];
        #pragma unroll
        for (int mi = 0; mi < 4; ++mi)
            af[mi] = *(const bf16x8*)&As[wr * 64 + mi * 16 + lr][lg * 8];
        #pragma unroll
        for (int ni = 0; ni < 4; ++ni)
            bfr[ni] = *(const bf16x8*)&Bs[wc * 64 + ni * 16 + lr][lg * 8];
        #pragma unroll
        for (int mi = 0; mi < 4; ++mi)
            #pragma unroll
            for (int ni = 0; ni < 4; ++ni)
                acc[mi][ni] = mfma16(af[mi], bfr[ni], acc[mi][ni]);
    }

    #pragma unroll
    for (int mi = 0; mi < 4; ++mi) {
        #pragma unroll
        for (int ni = 0; ni < 4; ++ni) {
            int col = bn + wc * 64 + ni * 16 + lr;
            float bsv = bias[col];
            #pragma unroll
            for (int r = 0; r < 4; ++r) {
                int row = bm + wr * 64 + mi * 16 + lg * 4 + r;
                float v = acc[mi][ni][r] + bsv;
                if (OMODE == 2) v = 0.5f * v * (1.0f + erff(v * 0.70710678118654752f));
                if (OMODE == 0)
                    ((float*)Cout)[(size_t)row * N + col] = v;
                else
                    ((bf16*)Cout)[(size_t)row * N + col] = (bf16)v;
            }
        }
    }
}

// ------------- flash attention: LDS-staged K/V (shared by 4 waves), KVB=64 -------------
// K,V staged coalescedly via global_load_lds with pre-swizzled SOURCE chunks
// (LDS dest linear; content XOR-permuted within each 128B row). Swapped QK^T,
// in-register softmax (exp2 domain), defer-max, in-register P repack.
#define C2F 0.18033688011112f   /* 0.125 * log2(e) */
#define THR2 11.5416f           /* 8 * log2(e) */
__global__ __launch_bounds__(256, 3) void attn_kernel(const bf16* __restrict__ qkvb,
                                                      const bf16* __restrict__ vt,
                                                      bf16* __restrict__ outb) {
    __shared__ __align__(16) bf16 Kl[2][64 * 64];
    __shared__ __align__(16) bf16 Vl[2][64 * 64];
    const int tid = threadIdx.x;
    const int w = tid >> 6, lane = tid & 63;
    const int lq = lane & 31;
    const int hi = lane >> 5;
    const int lin = blockIdx.x;
    const int xcd = lin & 7, slot = lin >> 3;
    const int bh = xcd * 6 + (slot >> 4);
    const int qt = slot & 15;
    const int b = bh / NH, h = bh - b * NH;
    const int q0 = qt * 128 + w * 32;

    const bf16* qbase = qkvb + (size_t)b * SEQ * C3 + h * HD;
    const bf16* kbase = qbase + CH;
    const bf16* vbase = vt + (size_t)bh * HD * SEQ;

    // staging sources: thread t -> row srow/srow+32, lds chunk (t&7),
    // source chunk (t&7)^(srow&7)  [same for K rows and V d-rows]
    const int srow = tid >> 3;
    const int ksc = (tid & 7) ^ (srow & 7);
    const bf16* gk0 = kbase + (size_t)srow * C3 + ksc * 8;
    const bf16* gk1 = kbase + (size_t)(srow + 32) * C3 + ksc * 8;
    const bf16* gv0 = vbase + (size_t)srow * SEQ + ksc * 8;
    const bf16* gv1 = vbase + (size_t)(srow + 32) * SEQ + ksc * 8;
    const int ldst = tid * 8;   // element offset (16B per thread)

    // Q fragments (once)
    bf16x8 qf[4];
    #pragma unroll
    for (int ks = 0; ks < 4; ++ks)
        qf[ks] = *(const bf16x8*)&qbase[(size_t)(q0 + lq) * C3 + ks * 16 + hi * 8];

    f32x16 o0 = {0.f}, o1 = {0.f};
    float m = -3.0e38f, l = 0.f;

    const int swz = lq & 7;

    auto stage = [&](int buf, int kv0) {
        gload16(gk0 + (size_t)kv0 * C3, &Kl[buf][ldst]);
        gload16(gk1 + (size_t)kv0 * C3, &Kl[buf][2048 + ldst]);
        gload16(gv0 + kv0, &Vl[buf][ldst]);
        gload16(gv1 + kv0, &Vl[buf][2048 + ldst]);
    };

    auto process = [&](const bf16* Kb, const bf16* Vb) {
        // ---- QK^T: st0 = rows kv 0-31, st1 = rows kv 32-63 ----
        f32x16 st0 = {0.f}, st1 = {0.f};
        #pragma unroll
        for (int ks = 0; ks < 4; ++ks) {
            int c = 8 * ((2 * ks + hi) ^ swz);
            bf16x8 k0 = *(const bf16x8*)&Kb[lq * 64 + c];
            bf16x8 k1 = *(const bf16x8*)&Kb[(32 + lq) * 64 + c];
            st0 = mfma32(k0, qf[ks], st0);
            st1 = mfma32(k1, qf[ks], st1);
        }
        // ---- max over 64 kv ----
        float t_[8];
        #pragma unroll
        for (int r = 0; r < 8; ++r)
            t_[r] = fmaxf(fmaxf(st0[r], st0[r + 8]), fmaxf(st1[r], st1[r + 8]));
        #pragma unroll
        for (int r = 0; r < 4; ++r) t_[r] = fmaxf(t_[r], t_[r + 4]);
        float mx = fmaxf(fmaxf(t_[0], t_[1]), fmaxf(t_[2], t_[3]));
        mx = fmaxf(mx, __shfl_xor(mx, 32));
        float m2x = mx * C2F;
        // ---- defer-max rescale ----
        if (!__all(m2x <= m + THR2)) {
            float mn = fmaxf(m, m2x);
            float alpha = __builtin_amdgcn_exp2f(m - mn);
            m = mn;
            l *= alpha;
            #pragma unroll
            for (int r = 0; r < 16; ++r) {
                int qr = (r & 3) + 8 * (r >> 2) + 4 * hi;
                float ar = __shfl(alpha, qr);
                o0[r] *= ar;
                o1[r] *= ar;
            }
        }
        // ---- subtile 0: exp2, partial sum, pack -> pa0, pa1 ----
        bf16x8 pa[4];
        float ps0, ps1;
        {
            float p[16];
            #pragma unroll
            for (int r = 0; r < 16; ++r) p[r] = __builtin_amdgcn_exp2f(fmaf(st0[r], C2F, -m));
            float s0[8];
            #pragma unroll
            for (int r = 0; r < 8; ++r) s0[r] = p[r] + p[r + 8];
            #pragma unroll
            for (int r = 0; r < 4; ++r) s0[r] += s0[r + 4];
            ps0 = (s0[0] + s0[1]) + (s0[2] + s0[3]);
            int a[8];
            #pragma unroll
            for (int i = 0; i < 8; ++i) {
                bf16x2 t2 = {(bf16)p[2 * i], (bf16)p[2 * i + 1]};
                a[i] = __builtin_bit_cast(int, t2);
            }
            int d0 = __shfl_xor(hi ? a[0] : a[2], 32);
            int d1 = __shfl_xor(hi ? a[1] : a[3], 32);
            int d2 = __shfl_xor(hi ? a[4] : a[6], 32);
            int d3 = __shfl_xor(hi ? a[5] : a[7], 32);
            intx4 f0 = hi ? (intx4){d0, d1, a[2], a[3]} : (intx4){a[0], a[1], d0, d1};
            intx4 f1 = hi ? (intx4){d2, d3, a[6], a[7]} : (intx4){a[4], a[5], d2, d3};
            pa[0] = __builtin_bit_cast(bf16x8, f0);
            pa[1] = __builtin_bit_cast(bf16x8, f1);
        }
        // ---- subtile 1: exp2, partial sum, pack -> pa2, pa3 ----
        {
            float p[16];
            #pragma unroll
            for (int r = 0; r < 16; ++r) p[r] = __builtin_amdgcn_exp2f(fmaf(st1[r], C2F, -m));
            float s0[8];
            #pragma unroll
            for (int r = 0; r < 8; ++r) s0[r] = p[r] + p[r + 8];
            #pragma unroll
            for (int r = 0; r < 4; ++r) s0[r] += s0[r + 4];
            ps1 = (s0[0] + s0[1]) + (s0[2] + s0[3]);
            int a[8];
            #pragma unroll
            for (int i = 0; i < 8; ++i) {
                bf16x2 t2 = {(bf16)p[2 * i], (bf16)p[2 * i + 1]};
                a[i] = __builtin_bit_cast(int, t2);
            }
            int d0 = __shfl_xor(hi ? a[0] : a[2], 32);
            int d1 = __shfl_xor(hi ? a[1] : a[3], 32);
            int d2 = __shfl_xor(hi ? a[4] : a[6], 32);
            int d3 = __shfl_xor(hi ? a[5] : a[7], 32);
            intx4 f0 = hi ? (intx4){d0, d1, a[2], a[3]} : (intx4){a[0], a[1], d0, d1};
            intx4 f1 = hi ? (intx4){d2, d3, a[6], a[7]} : (intx4){a[4], a[5], d2, d3};
            pa[2] = __builtin_bit_cast(bf16x8, f0);
            pa[3] = __builtin_bit_cast(bf16x8, f1);
        }
        float ps = ps0 + ps1;
        ps += __shfl_xor(ps, 32);
        l += ps;
        // ---- PV: 4 kv-chunks of 16 ----
        #pragma unroll
        for (int c = 0; c < 4; ++c) {
            int cc = 8 * ((2 * c + hi) ^ swz);
            bf16x8 v0 = *(const bf16x8*)&Vb[lq * 64 + cc];
            bf16x8 v1 = *(const bf16x8*)&Vb[(32 + lq) * 64 + cc];
            o0 = mfma32(pa[c], v0, o0);
            o1 = mfma32(pa[c], v1, o1);
        }
    };

    stage(0, 0);
    __syncthreads();
    for (int t = 0; t < 32; t += 2) {
        stage(1, (t + 1) * 64);
        process(Kl[0], Vl[0]);
        __syncthreads();
        stage(0, (t + 2 < 32 ? t + 2 : 31) * 64);
        process(Kl[1], Vl[1]);
        __syncthreads();
    }

    float linv = 1.0f / l;
    const size_t obase = (size_t)b * SEQ * CH + h * HD;
    #pragma unroll
    for (int r = 0; r < 16; ++r) {
        int qr = (r & 3) + 8 * (r >> 2) + 4 * hi;
        float lr_ = __shfl(linv, qr);
        size_t rowo = obase + (size_t)(q0 + qr) * CH;
        outb[rowo + lq] = (bf16)(o0[r] * lr_);
        outb[rowo + 32 + lq] = (bf16)(o1[r] * lr_);
    }
}

// ------------- fused residual add + LayerNorm -------------
__global__ __launch_bounds__(256) void add_ln(const float* __restrict__ x,
                                              const float* __restrict__ t,
                                              const float* __restrict__ g,
                                              const float* __restrict__ bt,
                                              float* __restrict__ y,
                                              bf16* __restrict__ yb) {
    const int row = blockIdx.x;
    const size_t base = (size_t)row * CH;
    const int tid = threadIdx.x;
    float v[3];
    #pragma unroll
    for (int k = 0; k < 3; ++k) {
        int c = tid + k * 256;
        v[k] = x[base + c] + t[base + c];
    }
    __shared__ float red[4];
    float s = v[0] + v[1] + v[2];
    #pragma unroll
    for (int off = 32; off >= 1; off >>= 1) s += __shfl_down(s, off);
    if ((tid & 63) == 0) red[tid >> 6] = s;
    __syncthreads();
    float mean = (red[0] + red[1] + red[2] + red[3]) * (1.0f / 768.0f);
    float q = 0.f;
    #pragma unroll
    for (int k = 0; k < 3; ++k) {
        float d = v[k] - mean;
        q += d * d;
    }
    __syncthreads();
    #pragma unroll
    for (int off = 32; off >= 1; off >>= 1) q += __shfl_down(q, off);
    if ((tid & 63) == 0) red[tid >> 6] = q;
    __syncthreads();
    float var = (red[0] + red[1] + red[2] + red[3]) * (1.0f / 768.0f);
    float rstd = rsqrtf(var + 1e-5f);
    #pragma unroll
    for (int k = 0; k < 3; ++k) {
        int c = tid + k * 256;
        float out = (v[k] - mean) * rstd * g[c] + bt[c];
        y[base + c] = out;
        if (yb) yb[base + c] = (bf16)out;
    }
}

extern "C" void kernel_launch(void* const* d_in, const int* in_sizes, int n_in,
                              void* d_out, int out_size, void* d_ws, size_t ws_size,
                              hipStream_t stream) {
    const float* x    = (const float*)d_in[0];
    const float* Wqkv = (const float*)d_in[1];
    const float* bqkv = (const float*)d_in[2];
    const float* Wproj= (const float*)d_in[3];
    const float* bproj= (const float*)d_in[4];
    const float* g1   = (const float*)d_in[5];
    const float* b1   = (const float*)d_in[6];
    const float* g2   = (const float*)d_in[7];
    const float* b2   = (const float*)d_in[8];
    const float* Wfc1 = (const float*)d_in[9];
    const float* bfc1 = (const float*)d_in[10];
    const float* Wfc2 = (const float*)d_in[11];
    const float* bfc2 = (const float*)d_in[12];

    char* ws = (char*)d_ws;
    size_t off = 0;
    auto alloc = [&](size_t bytes) -> void* {
        void* p = ws + off;
        off += (bytes + 255) & ~(size_t)255;
        return p;
    };

    bf16* xb     = (bf16*)alloc((size_t)MROWS * CH * 2);
    bf16* WqkvT  = (bf16*)alloc((size_t)C3 * CH * 2);
    bf16* WprojT = (bf16*)alloc((size_t)CH * CH * 2);
    bf16* Wfc1T  = (bf16*)alloc((size_t)DFF * CH * 2);
    bf16* Wfc2T  = (bf16*)alloc((size_t)CH * DFF * 2);
    bf16* qkvb   = (bf16*)alloc((size_t)MROWS * C3 * 2);
    bf16* vtb    = (bf16*)alloc((size_t)BB * NH * HD * SEQ * 2);
    bf16* attnb  = (bf16*)alloc((size_t)MROWS * CH * 2);
    float* tmp   = (float*)alloc((size_t)MROWS * CH * 4);
    float* y1    = (float*)alloc((size_t)MROWS * CH * 4);
    bf16* y1b    = (bf16*)alloc((size_t)MROWS * CH * 2);
    bf16* hb     = (bf16*)alloc((size_t)MROWS * DFF * 2);

    cvt_f32_bf16<<<(MROWS * CH / 4 + 255) / 256, 256, 0, stream>>>(x, xb, MROWS * CH);
    transpose_cvt<<<dim3(C3 / 32, CH / 32), 256, 0, stream>>>(Wqkv, WqkvT, CH, C3);
    transpose_cvt<<<dim3(CH / 32, CH / 32), 256, 0, stream>>>(Wproj, WprojT, CH, CH);
    transpose_cvt<<<dim3(DFF / 32, CH / 32), 256, 0, stream>>>(Wfc1, Wfc1T, CH, DFF);
    transpose_cvt<<<dim3(CH / 32, DFF / 32), 256, 0, stream>>>(Wfc2, Wfc2T, DFF, CH);
    gemm_bt<1><<<dim3(C3 / 128, MROWS / 128), 256, 0, stream>>>(xb, WqkvT, bqkv, qkvb, MROWS, C3, CH);
    transpose_v<<<dim3(SEQ / 32, HD / 32, BB * NH), 256, 0, stream>>>(qkvb, vtb);
    attn_kernel<<<768, 256, 0, stream>>>(qkvb, vtb, attnb);
    gemm_bt<0><<<dim3(CH / 128, MROWS / 128), 256, 0, stream>>>(attnb, WprojT, bproj, tmp, MROWS, CH, CH);
    add_ln<<<MROWS, 256, 0, stream>>>(x, tmp, g1, b1, y1, y1b);
    gemm_bt<2><<<dim3(DFF / 128, MROWS / 128), 256, 0, stream>>>(y1b, Wfc1T, bfc1, hb, MROWS, DFF, CH);
    gemm_bt<0><<<dim3(CH / 128, MROWS / 128), 256, 0, stream>>>(hb, Wfc2T, bfc2, tmp, MROWS, CH, DFF);
    add_ln<<<MROWS, 256, 0, stream>>>(y1, tmp, g2, b2, (float*)d_out, nullptr);
}

// Round 5
// 339.723 us; speedup vs baseline: 1.8944x; 1.0403x over previous
//
#include <hip/hip_runtime.h>

typedef __bf16 bf16;
typedef __bf16 bf16x2 __attribute__((ext_vector_type(2)));
typedef __bf16 bf16x4 __attribute__((ext_vector_type(4)));
typedef __bf16 bf16x8 __attribute__((ext_vector_type(8)));
typedef float  f32x4  __attribute__((ext_vector_type(4)));
typedef float  f32x16 __attribute__((ext_vector_type(16)));
typedef int    intx4  __attribute__((ext_vector_type(4)));

#define BB 4
#define SEQ 2048
#define CH 768
#define NH 12
#define HD 64
#define DFF 3072
#define MROWS (BB * SEQ)   // 8192
#define C3 (3 * CH)        // 2304

__device__ inline f32x16 mfma32(bf16x8 a, bf16x8 b, f32x16 c) {
    return __builtin_amdgcn_mfma_f32_32x32x16_bf16(a, b, c, 0, 0, 0);
}
__device__ inline f32x4 mfma16(bf16x8 a, bf16x8 b, f32x4 c) {
    return __builtin_amdgcn_mfma_f32_16x16x32_bf16(a, b, c, 0, 0, 0);
}
__device__ inline void gload16(const void* g, void* l) {
    __builtin_amdgcn_global_load_lds((const __attribute__((address_space(1))) void*)g,
                                     (__attribute__((address_space(3))) void*)l, 16, 0, 0);
}

// ---------------- fp32 -> bf16 convert (vectorized x4) ----------------
__global__ void cvt_f32_bf16(const float* __restrict__ in, bf16* __restrict__ out, int n) {
    int i = (blockIdx.x * blockDim.x + threadIdx.x) * 4;
    if (i + 3 >= n) {
        for (int j = 0; j < 4 && i + j < n; ++j) out[i + j] = (bf16)in[i + j];
        return;
    }
    f32x4 v = *(const f32x4*)&in[i];
    bf16x4 o;
    #pragma unroll
    for (int j = 0; j < 4; ++j) o[j] = (bf16)v[j];
    *(bf16x4*)&out[i] = o;
}

// ------------- transpose + convert: in fp32 [R, Cc] -> out bf16 [Cc, R] -------------
__global__ void transpose_cvt(const float* __restrict__ in, bf16* __restrict__ out, int R, int Cc) {
    __shared__ bf16 t[32][33];
    int tx = threadIdx.x & 31, ty = threadIdx.x >> 5;
    int c0 = blockIdx.x * 32, r0 = blockIdx.y * 32;
    #pragma unroll
    for (int i = 0; i < 32; i += 8)
        t[ty + i][tx] = (bf16)in[(size_t)(r0 + ty + i) * Cc + c0 + tx];
    __syncthreads();
    #pragma unroll
    for (int i = 0; i < 32; i += 8)
        out[(size_t)(c0 + ty + i) * R + r0 + tx] = t[tx][ty + i];
}

// ------------- V transpose: qkvb [B,S,3C] (V slice) -> vt [B*H, 64, S] -------------
__global__ void transpose_v(const bf16* __restrict__ qkvb, bf16* __restrict__ vt) {
    __shared__ bf16 t[32][33];
    int tx = threadIdx.x & 31, ty = threadIdx.x >> 5;
    int n0 = blockIdx.x * 32, d0 = blockIdx.y * 32, bh = blockIdx.z;
    int b = bh / NH, h = bh - b * NH;
    #pragma unroll
    for (int i = 0; i < 32; i += 8)
        t[ty + i][tx] = qkvb[((size_t)b * SEQ + n0 + ty + i) * C3 + 2 * CH + h * HD + d0 + tx];
    __syncthreads();
    #pragma unroll
    for (int i = 0; i < 32; i += 8)
        vt[((size_t)bh * HD + d0 + ty + i) * SEQ + n0 + tx] = t[tx][ty + i];
}

// ------------- GEMM (m97 structure): C[M,N] = A[M,K] * Bt[N,K]^T + bias -------------
// OMODE: 0 fp32+bias, 1 bf16+bias, 2 bf16+bias+GELU, 3 fp32 split-K partial (no bias).
// K = per-z chunk length; lda = leading dim of A and Bt (full K). kbeg = z*K.
// XCD-chunked swizzle on (x,y) plane; requires gridDim.x*gridDim.y % 8 == 0.
template <int OMODE>
__global__ __launch_bounds__(256) void gemm_bt(const bf16* __restrict__ A,
                                               const bf16* __restrict__ Bt,
                                               const float* __restrict__ bias,
                                               void* __restrict__ Cout,
                                               int M, int N, int K, int lda) {
    __shared__ __align__(16) bf16 As[128][32];
    __shared__ __align__(16) bf16 Bs[128][32];
    const int nwg = gridDim.x * gridDim.y;
    const int orig = blockIdx.y * gridDim.x + blockIdx.x;
    const int wg = (orig & 7) * (nwg >> 3) + (orig >> 3);
    const int bm = (wg / gridDim.x) * 128, bn = (wg % gridDim.x) * 128;
    const int kbeg = blockIdx.z * K;
    const int tid = threadIdx.x;
    const int lane = tid & 63, w = tid >> 6;
    const int wr = w >> 1, wc = w & 1;
    const int lr = lane & 15, lg = lane >> 4;

    const int srow = tid >> 2, schk = (tid & 3) * 8;
    const bf16* gA0 = A + (size_t)(bm + srow) * lda + kbeg + schk;
    const bf16* gA1 = A + (size_t)(bm + 64 + srow) * lda + kbeg + schk;
    const bf16* gB0 = Bt + (size_t)(bn + srow) * lda + kbeg + schk;
    const bf16* gB1 = Bt + (size_t)(bn + 64 + srow) * lda + kbeg + schk;
    bf16* lA0 = &As[srow][schk];
    bf16* lA1 = &As[64 + srow][schk];
    bf16* lB0 = &Bs[srow][schk];
    bf16* lB1 = &Bs[64 + srow][schk];

    f32x4 acc[4][4];
    #pragma unroll
    for (int i = 0; i < 4; ++i)
        #pragma unroll
        for (int j = 0; j < 4; ++j) acc[i][j] = (f32x4){0.f, 0.f, 0.f, 0.f};

    for (int k0 = 0; k0 < K; k0 += 32) {
        __syncthreads();
        gload16(gA0, lA0); gload16(gA1, lA1);
        gload16(gB0, lB0); gload16(gB1, lB1);
        gA0 += 32; gA1 += 32; gB0 += 32; gB1 += 32;
        __syncthreads();
        bf16x8 af[4], bfr[4];
        #pragma unroll
        for (int mi = 0; mi < 4; ++mi)
            af[mi] = *(const bf16x8*)&As[wr * 64 + mi * 16 + lr][lg * 8];
        #pragma unroll
        for (int ni = 0; ni < 4; ++ni)
            bfr[ni] = *(const bf16x8*)&Bs[wc * 64 + ni * 16 + lr][lg * 8];
        #pragma unroll
        for (int mi = 0; mi < 4; ++mi)
            #pragma unroll
            for (int ni = 0; ni < 4; ++ni)
                acc[mi][ni] = mfma16(af[mi], bfr[ni], acc[mi][ni]);
    }

    float* outp = (float*)Cout;
    if (OMODE == 3) outp += (size_t)blockIdx.z * M * N;

    #pragma unroll
    for (int mi = 0; mi < 4; ++mi) {
        #pragma unroll
        for (int ni = 0; ni < 4; ++ni) {
            int col = bn + wc * 64 + ni * 16 + lr;
            float bsv = (OMODE == 3) ? 0.f : bias[col];
            #pragma unroll
            for (int r = 0; r < 4; ++r) {
                int row = bm + wr * 64 + mi * 16 + lg * 4 + r;
                float v = acc[mi][ni][r] + bsv;
                if (OMODE == 2) v = 0.5f * v * (1.0f + erff(v * 0.70710678118654752f));
                if (OMODE == 0 || OMODE == 3)
                    outp[(size_t)row * N + col] = v;
                else
                    ((bf16*)Cout)[(size_t)row * N + col] = (bf16)v;
            }
        }
    }
}

// ------------- flash attention: LDS-staged K/V (shared by 4 waves), KVB=64 -------------
#define C2F 0.18033688011112f   /* 0.125 * log2(e) */
#define THR2 11.5416f           /* 8 * log2(e) */
__global__ __launch_bounds__(256, 3) void attn_kernel(const bf16* __restrict__ qkvb,
                                                      const bf16* __restrict__ vt,
                                                      bf16* __restrict__ outb) {
    __shared__ __align__(16) bf16 Kl[2][64 * 64];
    __shared__ __align__(16) bf16 Vl[2][64 * 64];
    const int tid = threadIdx.x;
    const int w = tid >> 6, lane = tid & 63;
    const int lq = lane & 31;
    const int hi = lane >> 5;
    const int lin = blockIdx.x;
    const int xcd = lin & 7, slot = lin >> 3;
    const int bh = xcd * 6 + (slot >> 4);
    const int qt = slot & 15;
    const int b = bh / NH, h = bh - b * NH;
    const int q0 = qt * 128 + w * 32;

    const bf16* qbase = qkvb + (size_t)b * SEQ * C3 + h * HD;
    const bf16* kbase = qbase + CH;
    const bf16* vbase = vt + (size_t)bh * HD * SEQ;

    const int srow = tid >> 3;
    const int ksc = (tid & 7) ^ (srow & 7);
    const bf16* gk0 = kbase + (size_t)srow * C3 + ksc * 8;
    const bf16* gk1 = kbase + (size_t)(srow + 32) * C3 + ksc * 8;
    const bf16* gv0 = vbase + (size_t)srow * SEQ + ksc * 8;
    const bf16* gv1 = vbase + (size_t)(srow + 32) * SEQ + ksc * 8;
    const int ldst = tid * 8;

    bf16x8 qf[4];
    #pragma unroll
    for (int ks = 0; ks < 4; ++ks)
        qf[ks] = *(const bf16x8*)&qbase[(size_t)(q0 + lq) * C3 + ks * 16 + hi * 8];

    f32x16 o0 = {0.f}, o1 = {0.f};
    float m = -3.0e38f, l = 0.f;

    const int swz = lq & 7;

    auto stage = [&](int buf, int kv0) {
        gload16(gk0 + (size_t)kv0 * C3, &Kl[buf][ldst]);
        gload16(gk1 + (size_t)kv0 * C3, &Kl[buf][2048 + ldst]);
        gload16(gv0 + kv0, &Vl[buf][ldst]);
        gload16(gv1 + kv0, &Vl[buf][2048 + ldst]);
    };

    auto process = [&](const bf16* Kb, const bf16* Vb) {
        f32x16 st0 = {0.f}, st1 = {0.f};
        #pragma unroll
        for (int ks = 0; ks < 4; ++ks) {
            int c = 8 * ((2 * ks + hi) ^ swz);
            bf16x8 k0 = *(const bf16x8*)&Kb[lq * 64 + c];
            bf16x8 k1 = *(const bf16x8*)&Kb[(32 + lq) * 64 + c];
            st0 = mfma32(k0, qf[ks], st0);
            st1 = mfma32(k1, qf[ks], st1);
        }
        float t_[8];
        #pragma unroll
        for (int r = 0; r < 8; ++r)
            t_[r] = fmaxf(fmaxf(st0[r], st0[r + 8]), fmaxf(st1[r], st1[r + 8]));
        #pragma unroll
        for (int r = 0; r < 4; ++r) t_[r] = fmaxf(t_[r], t_[r + 4]);
        float mx = fmaxf(fmaxf(t_[0], t_[1]), fmaxf(t_[2], t_[3]));
        mx = fmaxf(mx, __shfl_xor(mx, 32));
        float m2x = mx * C2F;
        if (!__all(m2x <= m + THR2)) {
            float mn = fmaxf(m, m2x);
            float alpha = __builtin_amdgcn_exp2f(m - mn);
            m = mn;
            l *= alpha;
            #pragma unroll
            for (int r = 0; r < 16; ++r) {
                int qr = (r & 3) + 8 * (r >> 2) + 4 * hi;
                float ar = __shfl(alpha, qr);
                o0[r] *= ar;
                o1[r] *= ar;
            }
        }
        bf16x8 pa[4];
        float ps0, ps1;
        {
            float p[16];
            #pragma unroll
            for (int r = 0; r < 16; ++r) p[r] = __builtin_amdgcn_exp2f(fmaf(st0[r], C2F, -m));
            float s0[8];
            #pragma unroll
            for (int r = 0; r < 8; ++r) s0[r] = p[r] + p[r + 8];
            #pragma unroll
            for (int r = 0; r < 4; ++r) s0[r] += s0[r + 4];
            ps0 = (s0[0] + s0[1]) + (s0[2] + s0[3]);
            int a[8];
            #pragma unroll
            for (int i = 0; i < 8; ++i) {
                bf16x2 t2 = {(bf16)p[2 * i], (bf16)p[2 * i + 1]};
                a[i] = __builtin_bit_cast(int, t2);
            }
            int d0 = __shfl_xor(hi ? a[0] : a[2], 32);
            int d1 = __shfl_xor(hi ? a[1] : a[3], 32);
            int d2 = __shfl_xor(hi ? a[4] : a[6], 32);
            int d3 = __shfl_xor(hi ? a[5] : a[7], 32);
            intx4 f0 = hi ? (intx4){d0, d1, a[2], a[3]} : (intx4){a[0], a[1], d0, d1};
            intx4 f1 = hi ? (intx4){d2, d3, a[6], a[7]} : (intx4){a[4], a[5], d2, d3};
            pa[0] = __builtin_bit_cast(bf16x8, f0);
            pa[1] = __builtin_bit_cast(bf16x8, f1);
        }
        {
            float p[16];
            #pragma unroll
            for (int r = 0; r < 16; ++r) p[r] = __builtin_amdgcn_exp2f(fmaf(st1[r], C2F, -m));
            float s0[8];
            #pragma unroll
            for (int r = 0; r < 8; ++r) s0[r] = p[r] + p[r + 8];
            #pragma unroll
            for (int r = 0; r < 4; ++r) s0[r] += s0[r + 4];
            ps1 = (s0[0] + s0[1]) + (s0[2] + s0[3]);
            int a[8];
            #pragma unroll
            for (int i = 0; i < 8; ++i) {
                bf16x2 t2 = {(bf16)p[2 * i], (bf16)p[2 * i + 1]};
                a[i] = __builtin_bit_cast(int, t2);
            }
            int d0 = __shfl_xor(hi ? a[0] : a[2], 32);
            int d1 = __shfl_xor(hi ? a[1] : a[3], 32);
            int d2 = __shfl_xor(hi ? a[4] : a[6], 32);
            int d3 = __shfl_xor(hi ? a[5] : a[7], 32);
            intx4 f0 = hi ? (intx4){d0, d1, a[2], a[3]} : (intx4){a[0], a[1], d0, d1};
            intx4 f1 = hi ? (intx4){d2, d3, a[6], a[7]} : (intx4){a[4], a[5], d2, d3};
            pa[2] = __builtin_bit_cast(bf16x8, f0);
            pa[3] = __builtin_bit_cast(bf16x8, f1);
        }
        float ps = ps0 + ps1;
        ps += __shfl_xor(ps, 32);
        l += ps;
        #pragma unroll
        for (int c = 0; c < 4; ++c) {
            int cc = 8 * ((2 * c + hi) ^ swz);
            bf16x8 v0 = *(const bf16x8*)&Vb[lq * 64 + cc];
            bf16x8 v1 = *(const bf16x8*)&Vb[(32 + lq) * 64 + cc];
            o0 = mfma32(pa[c], v0, o0);
            o1 = mfma32(pa[c], v1, o1);
        }
    };

    stage(0, 0);
    __syncthreads();
    for (int t = 0; t < 32; t += 2) {
        stage(1, (t + 1) * 64);
        process(Kl[0], Vl[0]);
        __syncthreads();
        stage(0, (t + 2 < 32 ? t + 2 : 31) * 64);
        process(Kl[1], Vl[1]);
        __syncthreads();
    }

    float linv = 1.0f / l;
    const size_t obase = (size_t)b * SEQ * CH + h * HD;
    #pragma unroll
    for (int r = 0; r < 16; ++r) {
        int qr = (r & 3) + 8 * (r >> 2) + 4 * hi;
        float lr_ = __shfl(linv, qr);
        size_t rowo = obase + (size_t)(q0 + qr) * CH;
        outb[rowo + lq] = (bf16)(o0[r] * lr_);
        outb[rowo + 32 + lq] = (bf16)(o1[r] * lr_);
    }
}

// ------------- fused residual add + split-K reduce + bias + LayerNorm -------------
__global__ __launch_bounds__(256) void add_ln(const float* __restrict__ x,
                                              const float* __restrict__ t0,
                                              const float* __restrict__ t1,
                                              const float* __restrict__ bias,
                                              const float* __restrict__ g,
                                              const float* __restrict__ bt,
                                              float* __restrict__ y,
                                              bf16* __restrict__ yb) {
    const int row = blockIdx.x;
    const size_t base = (size_t)row * CH;
    const int tid = threadIdx.x;
    float v[3];
    #pragma unroll
    for (int k = 0; k < 3; ++k) {
        int c = tid + k * 256;
        float acc = x[base + c] + t0[base + c];
        if (t1) acc += t1[base + c];
        if (bias) acc += bias[c];
        v[k] = acc;
    }
    __shared__ float red[4];
    float s = v[0] + v[1] + v[2];
    #pragma unroll
    for (int off = 32; off >= 1; off >>= 1) s += __shfl_down(s, off);
    if ((tid & 63) == 0) red[tid >> 6] = s;
    __syncthreads();
    float mean = (red[0] + red[1] + red[2] + red[3]) * (1.0f / 768.0f);
    float q = 0.f;
    #pragma unroll
    for (int k = 0; k < 3; ++k) {
        float d = v[k] - mean;
        q += d * d;
    }
    __syncthreads();
    #pragma unroll
    for (int off = 32; off >= 1; off >>= 1) q += __shfl_down(q, off);
    if ((tid & 63) == 0) red[tid >> 6] = q;
    __syncthreads();
    float var = (red[0] + red[1] + red[2] + red[3]) * (1.0f / 768.0f);
    float rstd = rsqrtf(var + 1e-5f);
    #pragma unroll
    for (int k = 0; k < 3; ++k) {
        int c = tid + k * 256;
        float out = (v[k] - mean) * rstd * g[c] + bt[c];
        y[base + c] = out;
        if (yb) yb[base + c] = (bf16)out;
    }
}

extern "C" void kernel_launch(void* const* d_in, const int* in_sizes, int n_in,
                              void* d_out, int out_size, void* d_ws, size_t ws_size,
                              hipStream_t stream) {
    const float* x    = (const float*)d_in[0];
    const float* Wqkv = (const float*)d_in[1];
    const float* bqkv = (const float*)d_in[2];
    const float* Wproj= (const float*)d_in[3];
    const float* bproj= (const float*)d_in[4];
    const float* g1   = (const float*)d_in[5];
    const float* b1   = (const float*)d_in[6];
    const float* g2   = (const float*)d_in[7];
    const float* b2   = (const float*)d_in[8];
    const float* Wfc1 = (const float*)d_in[9];
    const float* bfc1 = (const float*)d_in[10];
    const float* Wfc2 = (const float*)d_in[11];
    const float* bfc2 = (const float*)d_in[12];

    char* ws = (char*)d_ws;
    size_t off = 0;
    auto alloc = [&](size_t bytes) -> void* {
        void* p = ws + off;
        off += (bytes + 255) & ~(size_t)255;
        return p;
    };

    bf16* xb     = (bf16*)alloc((size_t)MROWS * CH * 2);
    bf16* WqkvT  = (bf16*)alloc((size_t)C3 * CH * 2);
    bf16* WprojT = (bf16*)alloc((size_t)CH * CH * 2);
    bf16* Wfc1T  = (bf16*)alloc((size_t)DFF * CH * 2);
    bf16* Wfc2T  = (bf16*)alloc((size_t)CH * DFF * 2);
    bf16* qkvb   = (bf16*)alloc((size_t)MROWS * C3 * 2);
    bf16* vtb    = (bf16*)alloc((size_t)BB * NH * HD * SEQ * 2);
    bf16* attnb  = (bf16*)alloc((size_t)MROWS * CH * 2);
    float* tmpP  = (float*)alloc((size_t)2 * MROWS * CH * 4);  // contiguous split-K partial pair
    float* y1    = (float*)alloc((size_t)MROWS * CH * 4);
    bf16* y1b    = (bf16*)alloc((size_t)MROWS * CH * 2);
    bf16* hb     = (bf16*)alloc((size_t)MROWS * DFF * 2);

    cvt_f32_bf16<<<(MROWS * CH / 4 + 255) / 256, 256, 0, stream>>>(x, xb, MROWS * CH);
    transpose_cvt<<<dim3(C3 / 32, CH / 32), 256, 0, stream>>>(Wqkv, WqkvT, CH, C3);
    transpose_cvt<<<dim3(CH / 32, CH / 32), 256, 0, stream>>>(Wproj, WprojT, CH, CH);
    transpose_cvt<<<dim3(DFF / 32, CH / 32), 256, 0, stream>>>(Wfc1, Wfc1T, CH, DFF);
    transpose_cvt<<<dim3(CH / 32, DFF / 32), 256, 0, stream>>>(Wfc2, Wfc2T, DFF, CH);
    // qkv = x @ Wqkv + bqkv (bf16)
    gemm_bt<1><<<dim3(C3 / 128, MROWS / 128), 256, 0, stream>>>(xb, WqkvT, bqkv, qkvb, MROWS, C3, CH, CH);
    transpose_v<<<dim3(SEQ / 32, HD / 32, BB * NH), 256, 0, stream>>>(qkvb, vtb);
    attn_kernel<<<768, 256, 0, stream>>>(qkvb, vtb, attnb);
    // proj: split-K=2 in one dispatch (z selects K-chunk and partial buffer)
    gemm_bt<3><<<dim3(CH / 128, MROWS / 128, 2), 256, 0, stream>>>(attnb, WprojT, nullptr, tmpP, MROWS, CH, CH / 2, CH);
    // LN1: y1 = LN(x + projP0 + projP1 + bproj)
    add_ln<<<MROWS, 256, 0, stream>>>(x, tmpP, tmpP + (size_t)MROWS * CH, bproj, g1, b1, y1, y1b);
    // fc1 + GELU (bf16)
    gemm_bt<2><<<dim3(DFF / 128, MROWS / 128), 256, 0, stream>>>(y1b, Wfc1T, bfc1, hb, MROWS, DFF, CH, CH);
    // fc2: split-K=2 in one dispatch
    gemm_bt<3><<<dim3(CH / 128, MROWS / 128, 2), 256, 0, stream>>>(hb, Wfc2T, nullptr, tmpP, MROWS, CH, DFF / 2, DFF);
    // LN2 -> d_out
    add_ln<<<MROWS, 256, 0, stream>>>(y1, tmpP, tmpP + (size_t)MROWS * CH, bfc2, g2, b2, (float*)d_out, nullptr);
}

// Round 6
// 334.990 us; speedup vs baseline: 1.9212x; 1.0141x over previous
//
#include <hip/hip_runtime.h>

typedef __bf16 bf16;
typedef __bf16 bf16x2 __attribute__((ext_vector_type(2)));
typedef __bf16 bf16x4 __attribute__((ext_vector_type(4)));
typedef __bf16 bf16x8 __attribute__((ext_vector_type(8)));
typedef float  f32x4  __attribute__((ext_vector_type(4)));
typedef float  f32x16 __attribute__((ext_vector_type(16)));
typedef int    intx4  __attribute__((ext_vector_type(4)));

#define BB 4
#define SEQ 2048
#define CH 768
#define NH 12
#define HD 64
#define DFF 3072
#define MROWS (BB * SEQ)   // 8192
#define C3 (3 * CH)        // 2304

__device__ inline f32x16 mfma32(bf16x8 a, bf16x8 b, f32x16 c) {
    return __builtin_amdgcn_mfma_f32_32x32x16_bf16(a, b, c, 0, 0, 0);
}
__device__ inline f32x4 mfma16(bf16x8 a, bf16x8 b, f32x4 c) {
    return __builtin_amdgcn_mfma_f32_16x16x32_bf16(a, b, c, 0, 0, 0);
}
__device__ inline void gload16(const void* g, void* l) {
    __builtin_amdgcn_global_load_lds((const __attribute__((address_space(1))) void*)g,
                                     (__attribute__((address_space(3))) void*)l, 16, 0, 0);
}

// ---------------- fp32 -> bf16 convert (vectorized x4) ----------------
__global__ void cvt_f32_bf16(const float* __restrict__ in, bf16* __restrict__ out, int n) {
    int i = (blockIdx.x * blockDim.x + threadIdx.x) * 4;
    if (i + 3 >= n) {
        for (int j = 0; j < 4 && i + j < n; ++j) out[i + j] = (bf16)in[i + j];
        return;
    }
    f32x4 v = *(const f32x4*)&in[i];
    bf16x4 o;
    #pragma unroll
    for (int j = 0; j < 4; ++j) o[j] = (bf16)v[j];
    *(bf16x4*)&out[i] = o;
}

// ------------- transpose + convert: in fp32 [R, Cc] -> out bf16 [Cc, R] -------------
__global__ void transpose_cvt(const float* __restrict__ in, bf16* __restrict__ out, int R, int Cc) {
    __shared__ bf16 t[32][33];
    int tx = threadIdx.x & 31, ty = threadIdx.x >> 5;
    int c0 = blockIdx.x * 32, r0 = blockIdx.y * 32;
    #pragma unroll
    for (int i = 0; i < 32; i += 8)
        t[ty + i][tx] = (bf16)in[(size_t)(r0 + ty + i) * Cc + c0 + tx];
    __syncthreads();
    #pragma unroll
    for (int i = 0; i < 32; i += 8)
        out[(size_t)(c0 + ty + i) * R + r0 + tx] = t[tx][ty + i];
}

// ------------- V transpose: qkvb [B,S,3C] (V slice) -> vt [B*H, 64, S] -------------
__global__ void transpose_v(const bf16* __restrict__ qkvb, bf16* __restrict__ vt) {
    __shared__ bf16 t[32][33];
    int tx = threadIdx.x & 31, ty = threadIdx.x >> 5;
    int n0 = blockIdx.x * 32, d0 = blockIdx.y * 32, bh = blockIdx.z;
    int b = bh / NH, h = bh - b * NH;
    #pragma unroll
    for (int i = 0; i < 32; i += 8)
        t[ty + i][tx] = qkvb[((size_t)b * SEQ + n0 + ty + i) * C3 + 2 * CH + h * HD + d0 + tx];
    __syncthreads();
    #pragma unroll
    for (int i = 0; i < 32; i += 8)
        vt[((size_t)bh * HD + d0 + ty + i) * SEQ + n0 + tx] = t[tx][ty + i];
}

// ------------- GEMM (m97 + T3 dbuf): C[M,N] = A[M,K] * Bt[N,K]^T + bias -------------
// Double-buffered LDS, ONE barrier per K-step; stage(next) issued before
// compute(cur) so the compiler's vmcnt(0)-before-barrier drain lands after a
// full compute phase (staging latency hidden under MFMA).
// OMODE: 0 fp32+bias, 1 bf16+bias, 2 bf16+bias+GELU, 3 fp32 split-K partial.
template <int OMODE>
__global__ __launch_bounds__(256) void gemm_bt(const bf16* __restrict__ A,
                                               const bf16* __restrict__ Bt,
                                               const float* __restrict__ bias,
                                               void* __restrict__ Cout,
                                               int M, int N, int K, int lda) {
    __shared__ __align__(16) bf16 As[2][128][32];
    __shared__ __align__(16) bf16 Bs[2][128][32];
    const int nwg = gridDim.x * gridDim.y;
    const int orig = blockIdx.y * gridDim.x + blockIdx.x;
    const int wg = (orig & 7) * (nwg >> 3) + (orig >> 3);
    const int bm = (wg / gridDim.x) * 128, bn = (wg % gridDim.x) * 128;
    const int kbeg = blockIdx.z * K;
    const int tid = threadIdx.x;
    const int lane = tid & 63, w = tid >> 6;
    const int wr = w >> 1, wc = w & 1;
    const int lr = lane & 15, lg = lane >> 4;

    const int srow = tid >> 2, schk = (tid & 3) * 8;
    const bf16* gA0 = A + (size_t)(bm + srow) * lda + kbeg + schk;
    const bf16* gA1 = A + (size_t)(bm + 64 + srow) * lda + kbeg + schk;
    const bf16* gB0 = Bt + (size_t)(bn + srow) * lda + kbeg + schk;
    const bf16* gB1 = Bt + (size_t)(bn + 64 + srow) * lda + kbeg + schk;

    auto stage = [&](int buf, int kofs) {
        gload16(gA0 + kofs, &As[buf][srow][schk]);
        gload16(gA1 + kofs, &As[buf][64 + srow][schk]);
        gload16(gB0 + kofs, &Bs[buf][srow][schk]);
        gload16(gB1 + kofs, &Bs[buf][64 + srow][schk]);
    };

    f32x4 acc[4][4];
    #pragma unroll
    for (int i = 0; i < 4; ++i)
        #pragma unroll
        for (int j = 0; j < 4; ++j) acc[i][j] = (f32x4){0.f, 0.f, 0.f, 0.f};

    stage(0, 0);
    int cur = 0;
    for (int k0 = 0; k0 < K; k0 += 32) {
        __syncthreads();                    // drains stage(cur); prev compute done
        if (k0 + 32 < K) stage(cur ^ 1, k0 + 32);
        bf16x8 af[4], bfr[4];
        #pragma unroll
        for (int mi = 0; mi < 4; ++mi)
            af[mi] = *(const bf16x8*)&As[cur][wr * 64 + mi * 16 + lr][lg * 8];
        #pragma unroll
        for (int ni = 0; ni < 4; ++ni)
            bfr[ni] = *(const bf16x8*)&Bs[cur][wc * 64 + ni * 16 + lr][lg * 8];
        #pragma unroll
        for (int mi = 0; mi < 4; ++mi)
            #pragma unroll
            for (int ni = 0; ni < 4; ++ni)
                acc[mi][ni] = mfma16(af[mi], bfr[ni], acc[mi][ni]);
        cur ^= 1;
    }

    float* outp = (float*)Cout;
    if (OMODE == 3) outp += (size_t)blockIdx.z * M * N;

    #pragma unroll
    for (int mi = 0; mi < 4; ++mi) {
        #pragma unroll
        for (int ni = 0; ni < 4; ++ni) {
            int col = bn + wc * 64 + ni * 16 + lr;
            float bsv = (OMODE == 3) ? 0.f : bias[col];
            #pragma unroll
            for (int r = 0; r < 4; ++r) {
                int row = bm + wr * 64 + mi * 16 + lg * 4 + r;
                float v = acc[mi][ni][r] + bsv;
                if (OMODE == 2) v = 0.5f * v * (1.0f + erff(v * 0.70710678118654752f));
                if (OMODE == 0 || OMODE == 3)
                    outp[(size_t)row * N + col] = v;
                else
                    ((bf16*)Cout)[(size_t)row * N + col] = (bf16)v;
            }
        }
    }
}

// ------------- flash attention: LDS-staged K/V (shared by 4 waves), KVB=64 -------------
#define C2F 0.18033688011112f   /* 0.125 * log2(e) */
#define THR2 11.5416f           /* 8 * log2(e) */
__global__ __launch_bounds__(256, 3) void attn_kernel(const bf16* __restrict__ qkvb,
                                                      const bf16* __restrict__ vt,
                                                      bf16* __restrict__ outb) {
    __shared__ __align__(16) bf16 Kl[2][64 * 64];
    __shared__ __align__(16) bf16 Vl[2][64 * 64];
    const int tid = threadIdx.x;
    const int w = tid >> 6, lane = tid & 63;
    const int lq = lane & 31;
    const int hi = lane >> 5;
    const int lin = blockIdx.x;
    const int xcd = lin & 7, slot = lin >> 3;
    const int bh = xcd * 6 + (slot >> 4);
    const int qt = slot & 15;
    const int b = bh / NH, h = bh - b * NH;
    const int q0 = qt * 128 + w * 32;

    const bf16* qbase = qkvb + (size_t)b * SEQ * C3 + h * HD;
    const bf16* kbase = qbase + CH;
    const bf16* vbase = vt + (size_t)bh * HD * SEQ;

    const int srow = tid >> 3;
    const int ksc = (tid & 7) ^ (srow & 7);
    const bf16* gk0 = kbase + (size_t)srow * C3 + ksc * 8;
    const bf16* gk1 = kbase + (size_t)(srow + 32) * C3 + ksc * 8;
    const bf16* gv0 = vbase + (size_t)srow * SEQ + ksc * 8;
    const bf16* gv1 = vbase + (size_t)(srow + 32) * SEQ + ksc * 8;
    const int ldst = tid * 8;

    bf16x8 qf[4];
    #pragma unroll
    for (int ks = 0; ks < 4; ++ks)
        qf[ks] = *(const bf16x8*)&qbase[(size_t)(q0 + lq) * C3 + ks * 16 + hi * 8];

    f32x16 o0 = {0.f}, o1 = {0.f};
    float m = -3.0e38f, l = 0.f;

    const int swz = lq & 7;

    auto stage = [&](int buf, int kv0) {
        gload16(gk0 + (size_t)kv0 * C3, &Kl[buf][ldst]);
        gload16(gk1 + (size_t)kv0 * C3, &Kl[buf][2048 + ldst]);
        gload16(gv0 + kv0, &Vl[buf][ldst]);
        gload16(gv1 + kv0, &Vl[buf][2048 + ldst]);
    };

    auto process = [&](const bf16* Kb, const bf16* Vb) {
        f32x16 st0 = {0.f}, st1 = {0.f};
        __builtin_amdgcn_s_setprio(1);
        #pragma unroll
        for (int ks = 0; ks < 4; ++ks) {
            int c = 8 * ((2 * ks + hi) ^ swz);
            bf16x8 k0 = *(const bf16x8*)&Kb[lq * 64 + c];
            bf16x8 k1 = *(const bf16x8*)&Kb[(32 + lq) * 64 + c];
            st0 = mfma32(k0, qf[ks], st0);
            st1 = mfma32(k1, qf[ks], st1);
        }
        __builtin_amdgcn_s_setprio(0);
        // ---- in-lane max via v_max3 triples (cross-half shfl only on rescale) ----
        float a0 = fmaxf(fmaxf(st0[0], st0[1]), st0[2]);
        float a1 = fmaxf(fmaxf(st0[3], st0[4]), st0[5]);
        float a2 = fmaxf(fmaxf(st0[6], st0[7]), st0[8]);
        float a3 = fmaxf(fmaxf(st0[9], st0[10]), st0[11]);
        float a4 = fmaxf(fmaxf(st0[12], st0[13]), st0[14]);
        float a5 = fmaxf(fmaxf(st0[15], st1[0]), st1[1]);
        float a6 = fmaxf(fmaxf(st1[2], st1[3]), st1[4]);
        float a7 = fmaxf(fmaxf(st1[5], st1[6]), st1[7]);
        float a8 = fmaxf(fmaxf(st1[8], st1[9]), st1[10]);
        float a9 = fmaxf(fmaxf(st1[11], st1[12]), st1[13]);
        float a10 = fmaxf(st1[14], st1[15]);
        float b0 = fmaxf(fmaxf(a0, a1), a2);
        float b1 = fmaxf(fmaxf(a3, a4), a5);
        float b2 = fmaxf(fmaxf(a6, a7), a8);
        float lmax = fmaxf(fmaxf(b0, b1), fmaxf(b2, fmaxf(a9, a10)));
        float l2x = lmax * C2F;
        if (!__all(l2x <= m + THR2)) {
            float mx = fmaxf(lmax, __shfl_xor(lmax, 32));
            float mn = fmaxf(m, mx * C2F);
            float alpha = __builtin_amdgcn_exp2f(m - mn);
            m = mn;
            l *= alpha;
            #pragma unroll
            for (int r = 0; r < 16; ++r) {
                int qr = (r & 3) + 8 * (r >> 2) + 4 * hi;
                float ar = __shfl(alpha, qr);
                o0[r] *= ar;
                o1[r] *= ar;
            }
        }
        bf16x8 pa[4];
        float ps0, ps1;
        {
            float p[16];
            #pragma unroll
            for (int r = 0; r < 16; ++r) p[r] = __builtin_amdgcn_exp2f(fmaf(st0[r], C2F, -m));
            float s0[8];
            #pragma unroll
            for (int r = 0; r < 8; ++r) s0[r] = p[r] + p[r + 8];
            #pragma unroll
            for (int r = 0; r < 4; ++r) s0[r] += s0[r + 4];
            ps0 = (s0[0] + s0[1]) + (s0[2] + s0[3]);
            int a[8];
            #pragma unroll
            for (int i = 0; i < 8; ++i) {
                bf16x2 t2 = {(bf16)p[2 * i], (bf16)p[2 * i + 1]};
                a[i] = __builtin_bit_cast(int, t2);
            }
            int d0 = __shfl_xor(hi ? a[0] : a[2], 32);
            int d1 = __shfl_xor(hi ? a[1] : a[3], 32);
            int d2 = __shfl_xor(hi ? a[4] : a[6], 32);
            int d3 = __shfl_xor(hi ? a[5] : a[7], 32);
            intx4 f0 = hi ? (intx4){d0, d1, a[2], a[3]} : (intx4){a[0], a[1], d0, d1};
            intx4 f1 = hi ? (intx4){d2, d3, a[6], a[7]} : (intx4){a[4], a[5], d2, d3};
            pa[0] = __builtin_bit_cast(bf16x8, f0);
            pa[1] = __builtin_bit_cast(bf16x8, f1);
        }
        {
            float p[16];
            #pragma unroll
            for (int r = 0; r < 16; ++r) p[r] = __builtin_amdgcn_exp2f(fmaf(st1[r], C2F, -m));
            float s0[8];
            #pragma unroll
            for (int r = 0; r < 8; ++r) s0[r] = p[r] + p[r + 8];
            #pragma unroll
            for (int r = 0; r < 4; ++r) s0[r] += s0[r + 4];
            ps1 = (s0[0] + s0[1]) + (s0[2] + s0[3]);
            int a[8];
            #pragma unroll
            for (int i = 0; i < 8; ++i) {
                bf16x2 t2 = {(bf16)p[2 * i], (bf16)p[2 * i + 1]};
                a[i] = __builtin_bit_cast(int, t2);
            }
            int d0 = __shfl_xor(hi ? a[0] : a[2], 32);
            int d1 = __shfl_xor(hi ? a[1] : a[3], 32);
            int d2 = __shfl_xor(hi ? a[4] : a[6], 32);
            int d3 = __shfl_xor(hi ? a[5] : a[7], 32);
            intx4 f0 = hi ? (intx4){d0, d1, a[2], a[3]} : (intx4){a[0], a[1], d0, d1};
            intx4 f1 = hi ? (intx4){d2, d3, a[6], a[7]} : (intx4){a[4], a[5], d2, d3};
            pa[2] = __builtin_bit_cast(bf16x8, f0);
            pa[3] = __builtin_bit_cast(bf16x8, f1);
        }
        float ps = ps0 + ps1;
        ps += __shfl_xor(ps, 32);
        l += ps;
        __builtin_amdgcn_s_setprio(1);
        #pragma unroll
        for (int c = 0; c < 4; ++c) {
            int cc = 8 * ((2 * c + hi) ^ swz);
            bf16x8 v0 = *(const bf16x8*)&Vb[lq * 64 + cc];
            bf16x8 v1 = *(const bf16x8*)&Vb[(32 + lq) * 64 + cc];
            o0 = mfma32(pa[c], v0, o0);
            o1 = mfma32(pa[c], v1, o1);
        }
        __builtin_amdgcn_s_setprio(0);
    };

    stage(0, 0);
    __syncthreads();
    for (int t = 0; t < 32; t += 2) {
        stage(1, (t + 1) * 64);
        process(Kl[0], Vl[0]);
        __syncthreads();
        stage(0, (t + 2 < 32 ? t + 2 : 31) * 64);
        process(Kl[1], Vl[1]);
        __syncthreads();
    }

    float linv = 1.0f / l;
    const size_t obase = (size_t)b * SEQ * CH + h * HD;
    #pragma unroll
    for (int r = 0; r < 16; ++r) {
        int qr = (r & 3) + 8 * (r >> 2) + 4 * hi;
        float lr_ = __shfl(linv, qr);
        size_t rowo = obase + (size_t)(q0 + qr) * CH;
        outb[rowo + lq] = (bf16)(o0[r] * lr_);
        outb[rowo + 32 + lq] = (bf16)(o1[r] * lr_);
    }
}

// ------------- fused residual add + split-K reduce + bias + LayerNorm -------------
__global__ __launch_bounds__(256) void add_ln(const float* __restrict__ x,
                                              const float* __restrict__ t0,
                                              const float* __restrict__ t1,
                                              const float* __restrict__ bias,
                                              const float* __restrict__ g,
                                              const float* __restrict__ bt,
                                              float* __restrict__ y,
                                              bf16* __restrict__ yb) {
    const int row = blockIdx.x;
    const size_t base = (size_t)row * CH;
    const int tid = threadIdx.x;
    float v[3];
    #pragma unroll
    for (int k = 0; k < 3; ++k) {
        int c = tid + k * 256;
        float acc = x[base + c] + t0[base + c];
        if (t1) acc += t1[base + c];
        if (bias) acc += bias[c];
        v[k] = acc;
    }
    __shared__ float red[4];
    float s = v[0] + v[1] + v[2];
    #pragma unroll
    for (int off = 32; off >= 1; off >>= 1) s += __shfl_down(s, off);
    if ((tid & 63) == 0) red[tid >> 6] = s;
    __syncthreads();
    float mean = (red[0] + red[1] + red[2] + red[3]) * (1.0f / 768.0f);
    float q = 0.f;
    #pragma unroll
    for (int k = 0; k < 3; ++k) {
        float d = v[k] - mean;
        q += d * d;
    }
    __syncthreads();
    #pragma unroll
    for (int off = 32; off >= 1; off >>= 1) q += __shfl_down(q, off);
    if ((tid & 63) == 0) red[tid >> 6] = q;
    __syncthreads();
    float var = (red[0] + red[1] + red[2] + red[3]) * (1.0f / 768.0f);
    float rstd = rsqrtf(var + 1e-5f);
    #pragma unroll
    for (int k = 0; k < 3; ++k) {
        int c = tid + k * 256;
        float out = (v[k] - mean) * rstd * g[c] + bt[c];
        y[base + c] = out;
        if (yb) yb[base + c] = (bf16)out;
    }
}

extern "C" void kernel_launch(void* const* d_in, const int* in_sizes, int n_in,
                              void* d_out, int out_size, void* d_ws, size_t ws_size,
                              hipStream_t stream) {
    const float* x    = (const float*)d_in[0];
    const float* Wqkv = (const float*)d_in[1];
    const float* bqkv = (const float*)d_in[2];
    const float* Wproj= (const float*)d_in[3];
    const float* bproj= (const float*)d_in[4];
    const float* g1   = (const float*)d_in[5];
    const float* b1   = (const float*)d_in[6];
    const float* g2   = (const float*)d_in[7];
    const float* b2   = (const float*)d_in[8];
    const float* Wfc1 = (const float*)d_in[9];
    const float* bfc1 = (const float*)d_in[10];
    const float* Wfc2 = (const float*)d_in[11];
    const float* bfc2 = (const float*)d_in[12];

    char* ws = (char*)d_ws;
    size_t off = 0;
    auto alloc = [&](size_t bytes) -> void* {
        void* p = ws + off;
        off += (bytes + 255) & ~(size_t)255;
        return p;
    };

    bf16* xb     = (bf16*)alloc((size_t)MROWS * CH * 2);
    bf16* WqkvT  = (bf16*)alloc((size_t)C3 * CH * 2);
    bf16* WprojT = (bf16*)alloc((size_t)CH * CH * 2);
    bf16* Wfc1T  = (bf16*)alloc((size_t)DFF * CH * 2);
    bf16* Wfc2T  = (bf16*)alloc((size_t)CH * DFF * 2);
    bf16* qkvb   = (bf16*)alloc((size_t)MROWS * C3 * 2);
    bf16* vtb    = (bf16*)alloc((size_t)BB * NH * HD * SEQ * 2);
    bf16* attnb  = (bf16*)alloc((size_t)MROWS * CH * 2);
    float* tmpP  = (float*)alloc((size_t)2 * MROWS * CH * 4);  // contiguous split-K partial pair
    float* y1    = (float*)alloc((size_t)MROWS * CH * 4);
    bf16* y1b    = (bf16*)alloc((size_t)MROWS * CH * 2);
    bf16* hb     = (bf16*)alloc((size_t)MROWS * DFF * 2);

    cvt_f32_bf16<<<(MROWS * CH / 4 + 255) / 256, 256, 0, stream>>>(x, xb, MROWS * CH);
    transpose_cvt<<<dim3(C3 / 32, CH / 32), 256, 0, stream>>>(Wqkv, WqkvT, CH, C3);
    transpose_cvt<<<dim3(CH / 32, CH / 32), 256, 0, stream>>>(Wproj, WprojT, CH, CH);
    transpose_cvt<<<dim3(DFF / 32, CH / 32), 256, 0, stream>>>(Wfc1, Wfc1T, CH, DFF);
    transpose_cvt<<<dim3(CH / 32, DFF / 32), 256, 0, stream>>>(Wfc2, Wfc2T, DFF, CH);
    // qkv = x @ Wqkv + bqkv (bf16)
    gemm_bt<1><<<dim3(C3 / 128, MROWS / 128), 256, 0, stream>>>(xb, WqkvT, bqkv, qkvb, MROWS, C3, CH, CH);
    transpose_v<<<dim3(SEQ / 32, HD / 32, BB * NH), 256, 0, stream>>>(qkvb, vtb);
    attn_kernel<<<768, 256, 0, stream>>>(qkvb, vtb, attnb);
    // proj: split-K=2 in one dispatch (z selects K-chunk and partial buffer)
    gemm_bt<3><<<dim3(CH / 128, MROWS / 128, 2), 256, 0, stream>>>(attnb, WprojT, nullptr, tmpP, MROWS, CH, CH / 2, CH);
    // LN1: y1 = LN(x + projP0 + projP1 + bproj)
    add_ln<<<MROWS, 256, 0, stream>>>(x, tmpP, tmpP + (size_t)MROWS * CH, bproj, g1, b1, y1, y1b);
    // fc1 + GELU (bf16)
    gemm_bt<2><<<dim3(DFF / 128, MROWS / 128), 256, 0, stream>>>(y1b, Wfc1T, bfc1, hb, MROWS, DFF, CH, CH);
    // fc2: split-K=2 in one dispatch
    gemm_bt<3><<<dim3(CH / 128, MROWS / 128, 2), 256, 0, stream>>>(hb, Wfc2T, nullptr, tmpP, MROWS, CH, DFF / 2, DFF);
    // LN2 -> d_out
    add_ln<<<MROWS, 256, 0, stream>>>(y1, tmpP, tmpP + (size_t)MROWS * CH, bfc2, g2, b2, (float*)d_out, nullptr);
}

// Round 7
// 301.973 us; speedup vs baseline: 2.1313x; 1.1093x over previous
//
#include <hip/hip_runtime.h>

typedef __bf16 bf16;
typedef __bf16 bf16x2 __attribute__((ext_vector_type(2)));
typedef __bf16 bf16x4 __attribute__((ext_vector_type(4)));
typedef __bf16 bf16x8 __attribute__((ext_vector_type(8)));
typedef float  f32x4  __attribute__((ext_vector_type(4)));
typedef float  f32x16 __attribute__((ext_vector_type(16)));
typedef int    intx4  __attribute__((ext_vector_type(4)));

#define BB 4
#define SEQ 2048
#define CH 768
#define NH 12
#define HD 64
#define DFF 3072
#define MROWS (BB * SEQ)   // 8192
#define C3 (3 * CH)        // 2304

__device__ inline f32x16 mfma32(bf16x8 a, bf16x8 b, f32x16 c) {
    return __builtin_amdgcn_mfma_f32_32x32x16_bf16(a, b, c, 0, 0, 0);
}
__device__ inline f32x4 mfma16(bf16x8 a, bf16x8 b, f32x4 c) {
    return __builtin_amdgcn_mfma_f32_16x16x32_bf16(a, b, c, 0, 0, 0);
}
__device__ inline void gload16(const void* g, void* l) {
    __builtin_amdgcn_global_load_lds((const __attribute__((address_space(1))) void*)g,
                                     (__attribute__((address_space(3))) void*)l, 16, 0, 0);
}
// v_permlane32_swap_b32 (gfx950): dst rows 0-1 (lanes 0-31) exchange with
// src rows 2-3 (lanes 32-63). Both-copies idiom: x=y=v; after swap
// x[l] = v[l|32] (hi-broadcast), y[l] = v[l&31] (lo-broadcast). VALU pipe —
// replaces ds_bpermute-based __shfl_xor(.,32) on the softmax critical path.
__device__ inline void plswap_i(int& x, int& y) {
    asm volatile("v_permlane32_swap_b32 %0, %1" : "+v"(x), "+v"(y));
}
__device__ inline void plswap_f(float& x, float& y) {
    asm volatile("v_permlane32_swap_b32 %0, %1" : "+v"(x), "+v"(y));
}
__device__ inline int bcast_lo(int v) { int x = v, y = v; plswap_i(x, y); return y; }
__device__ inline int bcast_hi(int v) { int x = v, y = v; plswap_i(x, y); return x; }

// ---------------- fp32 -> bf16 convert (vectorized x4) ----------------
__global__ void cvt_f32_bf16(const float* __restrict__ in, bf16* __restrict__ out, int n) {
    int i = (blockIdx.x * blockDim.x + threadIdx.x) * 4;
    if (i + 3 >= n) {
        for (int j = 0; j < 4 && i + j < n; ++j) out[i + j] = (bf16)in[i + j];
        return;
    }
    f32x4 v = *(const f32x4*)&in[i];
    bf16x4 o;
    #pragma unroll
    for (int j = 0; j < 4; ++j) o[j] = (bf16)v[j];
    *(bf16x4*)&out[i] = o;
}

// ------------- transpose + convert: in fp32 [R, Cc] -> out bf16 [Cc, R] -------------
__global__ void transpose_cvt(const float* __restrict__ in, bf16* __restrict__ out, int R, int Cc) {
    __shared__ bf16 t[32][33];
    int tx = threadIdx.x & 31, ty = threadIdx.x >> 5;
    int c0 = blockIdx.x * 32, r0 = blockIdx.y * 32;
    #pragma unroll
    for (int i = 0; i < 32; i += 8)
        t[ty + i][tx] = (bf16)in[(size_t)(r0 + ty + i) * Cc + c0 + tx];
    __syncthreads();
    #pragma unroll
    for (int i = 0; i < 32; i += 8)
        out[(size_t)(c0 + ty + i) * R + r0 + tx] = t[tx][ty + i];
}

// ------------- V transpose: qkvb [B,S,3C] (V slice) -> vt [B*H, 64, S] -------------
__global__ void transpose_v(const bf16* __restrict__ qkvb, bf16* __restrict__ vt) {
    __shared__ bf16 t[32][33];
    int tx = threadIdx.x & 31, ty = threadIdx.x >> 5;
    int n0 = blockIdx.x * 32, d0 = blockIdx.y * 32, bh = blockIdx.z;
    int b = bh / NH, h = bh - b * NH;
    #pragma unroll
    for (int i = 0; i < 32; i += 8)
        t[ty + i][tx] = qkvb[((size_t)b * SEQ + n0 + ty + i) * C3 + 2 * CH + h * HD + d0 + tx];
    __syncthreads();
    #pragma unroll
    for (int i = 0; i < 32; i += 8)
        vt[((size_t)bh * HD + d0 + ty + i) * SEQ + n0 + tx] = t[tx][ty + i];
}

// ------------- GEMM (m97 + T3 dbuf): C[M,N] = A[M,K] * Bt[N,K]^T + bias -------------
// OMODE: 0 fp32+bias, 1 bf16+bias, 2 bf16+bias+GELU, 3 bf16 split-K partial (no bias).
template <int OMODE>
__global__ __launch_bounds__(256) void gemm_bt(const bf16* __restrict__ A,
                                               const bf16* __restrict__ Bt,
                                               const float* __restrict__ bias,
                                               void* __restrict__ Cout,
                                               int M, int N, int K, int lda) {
    __shared__ __align__(16) bf16 As[2][128][32];
    __shared__ __align__(16) bf16 Bs[2][128][32];
    const int nwg = gridDim.x * gridDim.y;
    const int orig = blockIdx.y * gridDim.x + blockIdx.x;
    const int wg = (orig & 7) * (nwg >> 3) + (orig >> 3);
    const int bm = (wg / gridDim.x) * 128, bn = (wg % gridDim.x) * 128;
    const int kbeg = blockIdx.z * K;
    const int tid = threadIdx.x;
    const int lane = tid & 63, w = tid >> 6;
    const int wr = w >> 1, wc = w & 1;
    const int lr = lane & 15, lg = lane >> 4;

    const int srow = tid >> 2, schk = (tid & 3) * 8;
    const bf16* gA0 = A + (size_t)(bm + srow) * lda + kbeg + schk;
    const bf16* gA1 = A + (size_t)(bm + 64 + srow) * lda + kbeg + schk;
    const bf16* gB0 = Bt + (size_t)(bn + srow) * lda + kbeg + schk;
    const bf16* gB1 = Bt + (size_t)(bn + 64 + srow) * lda + kbeg + schk;

    auto stage = [&](int buf, int kofs) {
        gload16(gA0 + kofs, &As[buf][srow][schk]);
        gload16(gA1 + kofs, &As[buf][64 + srow][schk]);
        gload16(gB0 + kofs, &Bs[buf][srow][schk]);
        gload16(gB1 + kofs, &Bs[buf][64 + srow][schk]);
    };

    f32x4 acc[4][4];
    #pragma unroll
    for (int i = 0; i < 4; ++i)
        #pragma unroll
        for (int j = 0; j < 4; ++j) acc[i][j] = (f32x4){0.f, 0.f, 0.f, 0.f};

    stage(0, 0);
    int cur = 0;
    for (int k0 = 0; k0 < K; k0 += 32) {
        __syncthreads();
        if (k0 + 32 < K) stage(cur ^ 1, k0 + 32);
        bf16x8 af[4], bfr[4];
        #pragma unroll
        for (int mi = 0; mi < 4; ++mi)
            af[mi] = *(const bf16x8*)&As[cur][wr * 64 + mi * 16 + lr][lg * 8];
        #pragma unroll
        for (int ni = 0; ni < 4; ++ni)
            bfr[ni] = *(const bf16x8*)&Bs[cur][wc * 64 + ni * 16 + lr][lg * 8];
        #pragma unroll
        for (int mi = 0; mi < 4; ++mi)
            #pragma unroll
            for (int ni = 0; ni < 4; ++ni)
                acc[mi][ni] = mfma16(af[mi], bfr[ni], acc[mi][ni]);
        cur ^= 1;
    }

    #pragma unroll
    for (int mi = 0; mi < 4; ++mi) {
        #pragma unroll
        for (int ni = 0; ni < 4; ++ni) {
            int col = bn + wc * 64 + ni * 16 + lr;
            float bsv = (OMODE == 3) ? 0.f : bias[col];
            #pragma unroll
            for (int r = 0; r < 4; ++r) {
                int row = bm + wr * 64 + mi * 16 + lg * 4 + r;
                float v = acc[mi][ni][r] + bsv;
                if (OMODE == 2) v = 0.5f * v * (1.0f + erff(v * 0.70710678118654752f));
                if (OMODE == 0)
                    ((float*)Cout)[(size_t)row * N + col] = v;
                else if (OMODE == 3)
                    ((bf16*)Cout)[(size_t)blockIdx.z * M * N + (size_t)row * N + col] = (bf16)v;
                else
                    ((bf16*)Cout)[(size_t)row * N + col] = (bf16)v;
            }
        }
    }
}

// ------------- flash attention: LDS-staged K/V, KVB=64, permlane softmax -------------
#define C2F 0.18033688011112f   /* 0.125 * log2(e) */
#define THR2 11.5416f           /* 8 * log2(e) */
__global__ __launch_bounds__(256, 3) void attn_kernel(const bf16* __restrict__ qkvb,
                                                      const bf16* __restrict__ vt,
                                                      bf16* __restrict__ outb) {
    __shared__ __align__(16) bf16 Kl[2][64 * 64];
    __shared__ __align__(16) bf16 Vl[2][64 * 64];
    const int tid = threadIdx.x;
    const int w = tid >> 6, lane = tid & 63;
    const int lq = lane & 31;
    const int hi = lane >> 5;
    const int lin = blockIdx.x;
    const int xcd = lin & 7, slot = lin >> 3;
    const int bh = xcd * 6 + (slot >> 4);
    const int qt = slot & 15;
    const int b = bh / NH, h = bh - b * NH;
    const int q0 = qt * 128 + w * 32;

    const bf16* qbase = qkvb + (size_t)b * SEQ * C3 + h * HD;
    const bf16* kbase = qbase + CH;
    const bf16* vbase = vt + (size_t)bh * HD * SEQ;

    const int srow = tid >> 3;
    const int ksc = (tid & 7) ^ (srow & 7);
    const bf16* gk0 = kbase + (size_t)srow * C3 + ksc * 8;
    const bf16* gk1 = kbase + (size_t)(srow + 32) * C3 + ksc * 8;
    const bf16* gv0 = vbase + (size_t)srow * SEQ + ksc * 8;
    const bf16* gv1 = vbase + (size_t)(srow + 32) * SEQ + ksc * 8;
    const int ldst = tid * 8;

    bf16x8 qf[4];
    #pragma unroll
    for (int ks = 0; ks < 4; ++ks)
        qf[ks] = *(const bf16x8*)&qbase[(size_t)(q0 + lq) * C3 + ks * 16 + hi * 8];

    f32x16 o0 = {0.f}, o1 = {0.f};
    float m = -3.0e38f, l = 0.f;

    const int swz = lq & 7;

    auto stage = [&](int buf, int kv0) {
        gload16(gk0 + (size_t)kv0 * C3, &Kl[buf][ldst]);
        gload16(gk1 + (size_t)kv0 * C3, &Kl[buf][2048 + ldst]);
        gload16(gv0 + kv0, &Vl[buf][ldst]);
        gload16(gv1 + kv0, &Vl[buf][2048 + ldst]);
    };

    auto process = [&](const bf16* Kb, const bf16* Vb) {
        f32x16 st0 = {0.f}, st1 = {0.f};
        #pragma unroll
        for (int ks = 0; ks < 4; ++ks) {
            int c = 8 * ((2 * ks + hi) ^ swz);
            bf16x8 k0 = *(const bf16x8*)&Kb[lq * 64 + c];
            bf16x8 k1 = *(const bf16x8*)&Kb[(32 + lq) * 64 + c];
            st0 = mfma32(k0, qf[ks], st0);
            st1 = mfma32(k1, qf[ks], st1);
        }
        // ---- row max over 64 kv: in-lane tree + 1 permlane swap ----
        float t_[8];
        #pragma unroll
        for (int r = 0; r < 8; ++r)
            t_[r] = fmaxf(fmaxf(st0[r], st0[r + 8]), fmaxf(st1[r], st1[r + 8]));
        #pragma unroll
        for (int r = 0; r < 4; ++r) t_[r] = fmaxf(t_[r], t_[r + 4]);
        float lmax = fmaxf(fmaxf(t_[0], t_[1]), fmaxf(t_[2], t_[3]));
        float mxa = lmax, mxb = lmax;
        plswap_f(mxa, mxb);
        float m2x = fmaxf(mxa, mxb) * C2F;   // full row max (both halves agree)
        if (!__all(m2x <= m + THR2)) {
            float mn = fmaxf(m, m2x);
            float alpha = __builtin_amdgcn_exp2f(m - mn);
            m = mn;
            l *= alpha;
            #pragma unroll
            for (int r = 0; r < 16; ++r) {
                int qr = (r & 3) + 8 * (r >> 2) + 4 * hi;
                float ar = __shfl(alpha, qr);
                o0[r] *= ar;
                o1[r] *= ar;
            }
        }
        // ---- subtiles: exp2, partial sums, pack via permlane broadcasts ----
        bf16x8 pa[4];
        float ps0, ps1;
        {
            float p[16];
            #pragma unroll
            for (int r = 0; r < 16; ++r) p[r] = __builtin_amdgcn_exp2f(fmaf(st0[r], C2F, -m));
            float s0[8];
            #pragma unroll
            for (int r = 0; r < 8; ++r) s0[r] = p[r] + p[r + 8];
            #pragma unroll
            for (int r = 0; r < 4; ++r) s0[r] += s0[r + 4];
            ps0 = (s0[0] + s0[1]) + (s0[2] + s0[3]);
            int a[8];
            #pragma unroll
            for (int i = 0; i < 8; ++i) {
                bf16x2 t2 = {(bf16)p[2 * i], (bf16)p[2 * i + 1]};
                a[i] = __builtin_bit_cast(int, t2);
            }
            // f0 = {a0[l&31], a1[l&31], a2[l|32], a3[l|32]}, f1 likewise on a4..a7
            intx4 f0 = {bcast_lo(a[0]), bcast_lo(a[1]), bcast_hi(a[2]), bcast_hi(a[3])};
            intx4 f1 = {bcast_lo(a[4]), bcast_lo(a[5]), bcast_hi(a[6]), bcast_hi(a[7])};
            pa[0] = __builtin_bit_cast(bf16x8, f0);
            pa[1] = __builtin_bit_cast(bf16x8, f1);
        }
        {
            float p[16];
            #pragma unroll
            for (int r = 0; r < 16; ++r) p[r] = __builtin_amdgcn_exp2f(fmaf(st1[r], C2F, -m));
            float s0[8];
            #pragma unroll
            for (int r = 0; r < 8; ++r) s0[r] = p[r] + p[r + 8];
            #pragma unroll
            for (int r = 0; r < 4; ++r) s0[r] += s0[r + 4];
            ps1 = (s0[0] + s0[1]) + (s0[2] + s0[3]);
            int a[8];
            #pragma unroll
            for (int i = 0; i < 8; ++i) {
                bf16x2 t2 = {(bf16)p[2 * i], (bf16)p[2 * i + 1]};
                a[i] = __builtin_bit_cast(int, t2);
            }
            intx4 f0 = {bcast_lo(a[0]), bcast_lo(a[1]), bcast_hi(a[2]), bcast_hi(a[3])};
            intx4 f1 = {bcast_lo(a[4]), bcast_lo(a[5]), bcast_hi(a[6]), bcast_hi(a[7])};
            pa[2] = __builtin_bit_cast(bf16x8, f0);
            pa[3] = __builtin_bit_cast(bf16x8, f1);
        }
        float ps = ps0 + ps1;
        float pa_ = ps, pb_ = ps;
        plswap_f(pa_, pb_);
        l += pa_ + pb_;
        #pragma unroll
        for (int c = 0; c < 4; ++c) {
            int cc = 8 * ((2 * c + hi) ^ swz);
            bf16x8 v0 = *(const bf16x8*)&Vb[lq * 64 + cc];
            bf16x8 v1 = *(const bf16x8*)&Vb[(32 + lq) * 64 + cc];
            o0 = mfma32(pa[c], v0, o0);
            o1 = mfma32(pa[c], v1, o1);
        }
    };

    stage(0, 0);
    __syncthreads();
    for (int t = 0; t < 32; t += 2) {
        stage(1, (t + 1) * 64);
        process(Kl[0], Vl[0]);
        __syncthreads();
        stage(0, (t + 2 < 32 ? t + 2 : 31) * 64);
        process(Kl[1], Vl[1]);
        __syncthreads();
    }

    float linv = 1.0f / l;
    const size_t obase = (size_t)b * SEQ * CH + h * HD;
    #pragma unroll
    for (int r = 0; r < 16; ++r) {
        int qr = (r & 3) + 8 * (r >> 2) + 4 * hi;
        float lr_ = __shfl(linv, qr);
        size_t rowo = obase + (size_t)(q0 + qr) * CH;
        outb[rowo + lq] = (bf16)(o0[r] * lr_);
        outb[rowo + 32 + lq] = (bf16)(o1[r] * lr_);
    }
}

// ------------- fused residual add + split-K reduce (bf16) + bias + LayerNorm -------------
// XBF16: residual input dtype (0=fp32, 1=bf16). OUTF32: output dtype.
template <int XBF16, int OUTF32>
__global__ __launch_bounds__(256) void add_ln(const void* __restrict__ xin,
                                              const bf16* __restrict__ t0,
                                              const bf16* __restrict__ t1,
                                              const float* __restrict__ bias,
                                              const float* __restrict__ g,
                                              const float* __restrict__ bt,
                                              void* __restrict__ yout) {
    const int row = blockIdx.x;
    const size_t base = (size_t)row * CH;
    const int tid = threadIdx.x;
    float v[3];
    #pragma unroll
    for (int k = 0; k < 3; ++k) {
        int c = tid + k * 256;
        float xv = XBF16 ? (float)((const bf16*)xin)[base + c]
                         : ((const float*)xin)[base + c];
        v[k] = xv + (float)t0[base + c] + (float)t1[base + c] + bias[c];
    }
    __shared__ float red[4];
    float s = v[0] + v[1] + v[2];
    #pragma unroll
    for (int off = 32; off >= 1; off >>= 1) s += __shfl_down(s, off);
    if ((tid & 63) == 0) red[tid >> 6] = s;
    __syncthreads();
    float mean = (red[0] + red[1] + red[2] + red[3]) * (1.0f / 768.0f);
    float q = 0.f;
    #pragma unroll
    for (int k = 0; k < 3; ++k) {
        float d = v[k] - mean;
        q += d * d;
    }
    __syncthreads();
    #pragma unroll
    for (int off = 32; off >= 1; off >>= 1) q += __shfl_down(q, off);
    if ((tid & 63) == 0) red[tid >> 6] = q;
    __syncthreads();
    float var = (red[0] + red[1] + red[2] + red[3]) * (1.0f / 768.0f);
    float rstd = rsqrtf(var + 1e-5f);
    #pragma unroll
    for (int k = 0; k < 3; ++k) {
        int c = tid + k * 256;
        float out = (v[k] - mean) * rstd * g[c] + bt[c];
        if (OUTF32) ((float*)yout)[base + c] = out;
        else        ((bf16*)yout)[base + c] = (bf16)out;
    }
}

extern "C" void kernel_launch(void* const* d_in, const int* in_sizes, int n_in,
                              void* d_out, int out_size, void* d_ws, size_t ws_size,
                              hipStream_t stream) {
    const float* x    = (const float*)d_in[0];
    const float* Wqkv = (const float*)d_in[1];
    const float* bqkv = (const float*)d_in[2];
    const float* Wproj= (const float*)d_in[3];
    const float* bproj= (const float*)d_in[4];
    const float* g1   = (const float*)d_in[5];
    const float* b1   = (const float*)d_in[6];
    const float* g2   = (const float*)d_in[7];
    const float* b2   = (const float*)d_in[8];
    const float* Wfc1 = (const float*)d_in[9];
    const float* bfc1 = (const float*)d_in[10];
    const float* Wfc2 = (const float*)d_in[11];
    const float* bfc2 = (const float*)d_in[12];

    char* ws = (char*)d_ws;
    size_t off = 0;
    auto alloc = [&](size_t bytes) -> void* {
        void* p = ws + off;
        off += (bytes + 255) & ~(size_t)255;
        return p;
    };

    bf16* xb     = (bf16*)alloc((size_t)MROWS * CH * 2);
    bf16* WqkvT  = (bf16*)alloc((size_t)C3 * CH * 2);
    bf16* WprojT = (bf16*)alloc((size_t)CH * CH * 2);
    bf16* Wfc1T  = (bf16*)alloc((size_t)DFF * CH * 2);
    bf16* Wfc2T  = (bf16*)alloc((size_t)CH * DFF * 2);
    bf16* qkvb   = (bf16*)alloc((size_t)MROWS * C3 * 2);
    bf16* vtb    = (bf16*)alloc((size_t)BB * NH * HD * SEQ * 2);
    bf16* attnb  = (bf16*)alloc((size_t)MROWS * CH * 2);
    bf16* tmpP   = (bf16*)alloc((size_t)2 * MROWS * CH * 2);  // bf16 split-K partial pair
    bf16* y1b    = (bf16*)alloc((size_t)MROWS * CH * 2);
    bf16* hb     = (bf16*)alloc((size_t)MROWS * DFF * 2);

    cvt_f32_bf16<<<(MROWS * CH / 4 + 255) / 256, 256, 0, stream>>>(x, xb, MROWS * CH);
    transpose_cvt<<<dim3(C3 / 32, CH / 32), 256, 0, stream>>>(Wqkv, WqkvT, CH, C3);
    transpose_cvt<<<dim3(CH / 32, CH / 32), 256, 0, stream>>>(Wproj, WprojT, CH, CH);
    transpose_cvt<<<dim3(DFF / 32, CH / 32), 256, 0, stream>>>(Wfc1, Wfc1T, CH, DFF);
    transpose_cvt<<<dim3(CH / 32, DFF / 32), 256, 0, stream>>>(Wfc2, Wfc2T, DFF, CH);
    // qkv = x @ Wqkv + bqkv (bf16)
    gemm_bt<1><<<dim3(C3 / 128, MROWS / 128), 256, 0, stream>>>(xb, WqkvT, bqkv, qkvb, MROWS, C3, CH, CH);
    transpose_v<<<dim3(SEQ / 32, HD / 32, BB * NH), 256, 0, stream>>>(qkvb, vtb);
    attn_kernel<<<768, 256, 0, stream>>>(qkvb, vtb, attnb);
    // proj: split-K=2, bf16 partials
    gemm_bt<3><<<dim3(CH / 128, MROWS / 128, 2), 256, 0, stream>>>(attnb, WprojT, nullptr, tmpP, MROWS, CH, CH / 2, CH);
    // LN1: y1b = LN(x + p0 + p1 + bproj)   (bf16 out only)
    add_ln<0, 0><<<MROWS, 256, 0, stream>>>(x, tmpP, tmpP + (size_t)MROWS * CH, bproj, g1, b1, y1b);
    // fc1 + GELU (bf16)
    gemm_bt<2><<<dim3(DFF / 128, MROWS / 128), 256, 0, stream>>>(y1b, Wfc1T, bfc1, hb, MROWS, DFF, CH, CH);
    // fc2: split-K=2, bf16 partials
    gemm_bt<3><<<dim3(CH / 128, MROWS / 128, 2), 256, 0, stream>>>(hb, Wfc2T, nullptr, tmpP, MROWS, CH, DFF / 2, DFF);
    // LN2 -> d_out (fp32), residual = y1b (bf16)
    add_ln<1, 1><<<MROWS, 256, 0, stream>>>(y1b, tmpP, tmpP + (size_t)MROWS * CH, bfc2, g2, b2, (float*)d_out);
}